// Round 4
// baseline (5663.304 us; speedup 1.0000x reference)
//
#include <hip/hip_runtime.h>

typedef unsigned short u16;
typedef __attribute__((ext_vector_type(8))) short short8;
typedef __attribute__((ext_vector_type(4))) float f32x4;
typedef __attribute__((ext_vector_type(2))) int i32x2;

#define NN 122880   // nodes per graph
#define EE 245760   // edges per graph
#define BB 4096     // reactions
#define HH 300      // hidden
#define LD 320      // padded feature leading dim (mult of 32)
#define NCP 384     // padded out-col count in WT slots
#define WTSL (NCP * LD)   // elements per transposed-weight slot
#define BHSZ (BB * HH)
#define GNB 16      // nodes per gather block
#define GB 6        // edges per forced-ILP batch (VGPR budget: ~170 <= 204 -> 2 blk/CU)

__device__ __forceinline__ float b2f(u16 s) {
  union { unsigned int u; float f; } v; v.u = ((unsigned int)s) << 16; return v.f;
}
__device__ __forceinline__ u16 f2b(float f) {
  union { float f; unsigned int u; } v; v.f = f;
  unsigned int r = v.u + 0x7FFFu + ((v.u >> 16) & 1u);
  return (u16)(r >> 16);
}

// ---------------------------------------------------------------------------
// prep: f32 weights -> zero-padded transposed bf16 WT[slot][n(384)][k(320)],
// f32 biases -> padded f32 bias[slot][384]. Slots: 0=Wn 1=We 2..4=W1 5..7=W2
// ---------------------------------------------------------------------------
__global__ __launch_bounds__(256) void prep_kernel(
    const float* __restrict__ Wn, const float* __restrict__ We,
    const float* __restrict__ W1, const float* __restrict__ W2,
    const float* __restrict__ bn, const float* __restrict__ be,
    const float* __restrict__ b1, const float* __restrict__ b2,
    u16* __restrict__ wtAll, float* __restrict__ biasAll)
{
  int idx = blockIdx.x * 256 + threadIdx.x;
  if (idx < 8 * WTSL) {
    int slot = idx / WTSL, rem = idx % WTSL;
    int n = rem / LD, k = rem % LD;
    float v = 0.f;
    if (n < HH) {
      if (slot == 0)      { if (k < 64)  v = Wn[k * HH + n]; }
      else if (slot == 1) { if (k < 16)  v = We[k * HH + n]; }
      else if (slot < 5)  { int l = slot - 2; if (k < HH) v = W1[(l * HH + k) * HH + n]; }
      else                { int l = slot - 5; if (k < HH) v = W2[(l * HH + k) * HH + n]; }
    }
    wtAll[idx] = f2b(v);
  } else {
    int j = idx - 8 * WTSL;
    if (j < 8 * NCP) {
      int slot = j / NCP, n = j % NCP;
      float v = 0.f;
      if (n < HH) {
        const float* bp = (slot == 0) ? bn : (slot == 1) ? be
                         : (slot < 5) ? (b1 + (slot - 2) * HH) : (b2 + (slot - 5) * HH);
        v = bp[n];
      }
      biasAll[j] = v;
    }
  }
}

__global__ __launch_bounds__(256) void zero_kernel(float4* __restrict__ p, int n4) {
  int i = blockIdx.x * 256 + threadIdx.x;
  if (i < n4) p[i] = make_float4(0.f, 0.f, 0.f, 0.f);
}

// ---------------------------------------------------------------------------
// CSR build: cursor doubles as counts; scan converts in place.
// fill writes int2{edge id, src id}, dst-sorted.
// ---------------------------------------------------------------------------
__global__ __launch_bounds__(256) void count_kernel(
    const int* __restrict__ dst, int* __restrict__ cursor)
{
  int e = blockIdx.x * 256 + threadIdx.x;
  if (e < EE) atomicAdd(&cursor[dst[e]], 1);
}

__global__ __launch_bounds__(1024) void scan_kernel(
    int* __restrict__ cursor, int* __restrict__ indptr)
{
  __shared__ int sd[1024];
  const int tid = threadIdx.x;
  const int base = tid * 120;          // 1024 * 120 == NN exactly
  int s = 0;
  for (int i = 0; i < 120; ++i) s += cursor[base + i];
  sd[tid] = s;
  __syncthreads();
  for (int off = 1; off < 1024; off <<= 1) {
    int v = (tid >= off) ? sd[tid - off] : 0;
    __syncthreads();
    sd[tid] += v;
    __syncthreads();
  }
  int run = sd[tid] - s;               // exclusive prefix
  for (int i = 0; i < 120; ++i) {
    int c = cursor[base + i];
    indptr[base + i] = run;
    cursor[base + i] = run;
    run += c;
  }
  if (tid == 1023) indptr[NN] = run;   // == EE
}

__global__ __launch_bounds__(256) void fill_kernel(
    const int* __restrict__ dst, const int* __restrict__ src,
    int* __restrict__ cursor, int2* __restrict__ ess)
{
  int e = blockIdx.x * 256 + threadIdx.x;
  if (e < EE) {
    int pos = atomicAdd(&cursor[dst[e]], 1);
    ess[pos] = make_int2(e, src[e]);
  }
}

// ---------------------------------------------------------------------------
// MFMA GEMM: C[r,c] = op(A[r,:K] @ W[:K,c] + bias[c]), bf16 out.
// A bf16 (a_f32=0) or f32 (a_f32=1, converted in staging). WT: [384][320]
// transposed bf16, zero pads. Block tile 128 rows x 160 cols (grid.y=2 covers
// 320 cols; pads 300..319 store exact 0). 4 waves 2x2, wave = 64x80 = 4x5
// MFMA 16x16x32 tiles.
// ---------------------------------------------------------------------------
__global__ __launch_bounds__(256) void gemm_kernel(
    const void* __restrict__ A, int lda, int K, int a_f32,
    const u16* __restrict__ WT, const float* __restrict__ bias,
    u16* __restrict__ C, int relu)
{
  __shared__ u16 As[128][40];   // +8 pad: rows 80B, 16B-aligned chunks
  __shared__ u16 Bs[160][40];

  const int tid = threadIdx.x;
  const int lane = tid & 63, w = tid >> 6;
  const int wm = (w >> 1) * 64, wn = (w & 1) * 80;
  const int m16 = lane & 15, q = lane >> 4;
  const long r0 = (long)blockIdx.x * 128;
  const int c0 = blockIdx.y * 160;

  f32x4 acc[4][5];
#pragma unroll
  for (int i = 0; i < 4; ++i)
#pragma unroll
    for (int j = 0; j < 5; ++j) acc[i][j] = (f32x4){0.f, 0.f, 0.f, 0.f};

  const int nk = K >> 5;
  for (int kt = 0; kt < nk; ++kt) {
    __syncthreads();
    // A tile: 128 rows x 32 k = 512 8-elem chunks
#pragma unroll
    for (int i = 0; i < 2; ++i) {
      int ci = tid + i * 256;
      int row = ci >> 2, kc = (ci & 3) << 3;
      int kg = (kt << 5) + kc;
      if (a_f32) {
        const float* Af = (const float*)A + (r0 + row) * (long)lda + kg;
        float4 v0 = *(const float4*)Af;
        float4 v1 = *(const float4*)(Af + 4);
        ushort4 p0, p1;
        p0.x = f2b(v0.x); p0.y = f2b(v0.y); p0.z = f2b(v0.z); p0.w = f2b(v0.w);
        p1.x = f2b(v1.x); p1.y = f2b(v1.y); p1.z = f2b(v1.z); p1.w = f2b(v1.w);
        *(ushort4*)&As[row][kc] = p0;
        *(ushort4*)&As[row][kc + 4] = p1;
      } else {
        uint4 av = *(const uint4*)((const u16*)A + (r0 + row) * (long)lda + kg);
        *(uint4*)&As[row][kc] = av;
      }
    }
    // B tile: 160 rows x 32 k = 640 chunks
#pragma unroll
    for (int i = 0; i < 3; ++i) {
      int ci = tid + i * 256;
      if (ci < 640) {
        int row = ci >> 2, kc = (ci & 3) << 3;
        int kg = (kt << 5) + kc;
        uint4 bv = *(const uint4*)(WT + (long)(c0 + row) * LD + kg);
        *(uint4*)&Bs[row][kc] = bv;
      }
    }
    __syncthreads();

    short8 af[4], bf[5];
#pragma unroll
    for (int t = 0; t < 4; ++t) af[t] = *(const short8*)&As[wm + t * 16 + m16][q << 3];
#pragma unroll
    for (int t = 0; t < 5; ++t) bf[t] = *(const short8*)&Bs[wn + t * 16 + m16][q << 3];
#pragma unroll
    for (int tm = 0; tm < 4; ++tm)
#pragma unroll
      for (int tn = 0; tn < 5; ++tn)
        acc[tm][tn] = __builtin_amdgcn_mfma_f32_16x16x32_bf16(af[tm], bf[tn], acc[tm][tn], 0, 0, 0);
  }

  // D row = q*4+i, col = lane&15 (m89/m91-verified C/D layout)
#pragma unroll
  for (int tn = 0; tn < 5; ++tn) {
    int c = c0 + wn + tn * 16 + m16;
    float bv = bias[c];
#pragma unroll
    for (int tm = 0; tm < 4; ++tm) {
      long rbase = r0 + wm + tm * 16 + q * 4;
#pragma unroll
      for (int i = 0; i < 4; ++i) {
        float v = acc[tm][tn][i] + bv;
        if (relu) v = v > 0.f ? v : 0.f;
        C[(rbase + i) * LD + c] = f2b(v);
      }
    }
  }
}

// ---------------------------------------------------------------------------
// gather: z[n] = h[n] + sum_{t: dst-sorted edges of n} relu(h[src]+eraw@We+be)
// Thread owns one column; register accumulator; no LDS.
// R3 post-mortem: compiler serialized the source-level 4-edge batch
// (VGPR_Count stayed 20 -> loads sunk to uses; per-edge ~1000cy chain
// exposed). This version FORCES 6 edges in flight with volatile inline-asm
// loads (volatile asms are not reordered among themselves), one
// s_waitcnt vmcnt(0) + sched_barrier(0) per batch (rule #18), and pipelines
// the next batch's ess loads under the current batch's eraw/h loads.
// Per-edge math order unchanged (bit-identical numerics).
// ---------------------------------------------------------------------------
#define EDGE_FETCH(i) \
    const float* rp##i = eraw + (long)E##i[0] * 16; \
    const u16*   hp##i = h + (long)E##i[1] * LD + c; \
    f32x4 V##i##0, V##i##1, V##i##2, V##i##3; unsigned int U##i; \
    asm volatile("global_load_dwordx4 %0, %1, off"           : "=v"(V##i##0) : "v"(rp##i)); \
    asm volatile("global_load_dwordx4 %0, %1, off offset:16" : "=v"(V##i##1) : "v"(rp##i)); \
    asm volatile("global_load_dwordx4 %0, %1, off offset:32" : "=v"(V##i##2) : "v"(rp##i)); \
    asm volatile("global_load_dwordx4 %0, %1, off offset:48" : "=v"(V##i##3) : "v"(rp##i)); \
    asm volatile("global_load_ushort %0, %1, off"            : "=v"(U##i)    : "v"(hp##i));

#define EDGE_MSG(i) \
    float m##i = bv; \
    m##i += V##i##0[0] * wreg[0];  m##i += V##i##0[1] * wreg[1];  \
    m##i += V##i##0[2] * wreg[2];  m##i += V##i##0[3] * wreg[3];  \
    m##i += V##i##1[0] * wreg[4];  m##i += V##i##1[1] * wreg[5];  \
    m##i += V##i##1[2] * wreg[6];  m##i += V##i##1[3] * wreg[7];  \
    m##i += V##i##2[0] * wreg[8];  m##i += V##i##2[1] * wreg[9];  \
    m##i += V##i##2[2] * wreg[10]; m##i += V##i##2[3] * wreg[11]; \
    m##i += V##i##3[0] * wreg[12]; m##i += V##i##3[1] * wreg[13]; \
    m##i += V##i##3[2] * wreg[14]; m##i += V##i##3[3] * wreg[15]; \
    m##i += b2f((u16)U##i);

#define ESS_ISSUE(tb) \
    asm volatile("global_load_dwordx2 %0, %1, off" : "=v"(E0) : "v"(ep + (((tb) + 0 < t1) ? (tb) + 0 : tl))); \
    asm volatile("global_load_dwordx2 %0, %1, off" : "=v"(E1) : "v"(ep + (((tb) + 1 < t1) ? (tb) + 1 : tl))); \
    asm volatile("global_load_dwordx2 %0, %1, off" : "=v"(E2) : "v"(ep + (((tb) + 2 < t1) ? (tb) + 2 : tl))); \
    asm volatile("global_load_dwordx2 %0, %1, off" : "=v"(E3) : "v"(ep + (((tb) + 3 < t1) ? (tb) + 3 : tl))); \
    asm volatile("global_load_dwordx2 %0, %1, off" : "=v"(E4) : "v"(ep + (((tb) + 4 < t1) ? (tb) + 4 : tl))); \
    asm volatile("global_load_dwordx2 %0, %1, off" : "=v"(E5) : "v"(ep + (((tb) + 5 < t1) ? (tb) + 5 : tl)));

#define VM_WAIT \
    asm volatile("s_waitcnt vmcnt(0)" ::: "memory"); \
    __builtin_amdgcn_sched_barrier(0);

__global__ __launch_bounds__(320) void gather_kernel(
    const u16* __restrict__ h, const float* __restrict__ eraw,
    const u16* __restrict__ wtE, const float* __restrict__ biasE,
    const int2* __restrict__ ess, const int* __restrict__ indptr,
    u16* __restrict__ z)
{
  const int base = blockIdx.x * GNB;
  const int c = threadIdx.x;

  float wreg[16];
  {
    uint4 w0 = *(const uint4*)(wtE + (long)c * LD);
    uint4 w1 = *(const uint4*)(wtE + (long)c * LD + 8);
    const u16* pw0 = (const u16*)&w0;
    const u16* pw1 = (const u16*)&w1;
#pragma unroll
    for (int k = 0; k < 8; ++k) { wreg[k] = b2f(pw0[k]); wreg[8 + k] = b2f(pw1[k]); }
  }
  const float bv = biasE[c];

  const int t0 = indptr[base];
  const int t1 = indptr[base + GNB];

  int g = 0;                              // current node within block
  int nxt = indptr[base + 1];             // end of current node's edge range
  float s = b2f(h[(long)base * LD + c]);  // z = h + agg, eps = 0

  if (t0 < t1) {
    const int tl = t1 - 1;
    const int2* ep = ess;
    i32x2 E0, E1, E2, E3, E4, E5;

    ESS_ISSUE(t0);
    VM_WAIT;

    for (int tb = t0; tb < t1; tb += GB) {
      // issue this batch's 24 eraw + 6 h loads (addresses from resolved E's)
      EDGE_FETCH(0); EDGE_FETCH(1); EDGE_FETCH(2);
      EDGE_FETCH(3); EDGE_FETCH(4); EDGE_FETCH(5);
      // pipeline next batch's ess under them (overwrites E's; addrs captured)
      if (tb + GB < t1) { ESS_ISSUE(tb + GB); }
      VM_WAIT;

      EDGE_MSG(0); EDGE_MSG(1); EDGE_MSG(2);
      EDGE_MSG(3); EDGE_MSG(4); EDGE_MSG(5);

#pragma unroll
      for (int j = 0; j < GB; ++j) {
        const float mj = (j == 0) ? m0 : (j == 1) ? m1 : (j == 2) ? m2
                       : (j == 3) ? m3 : (j == 4) ? m4 : m5;
        const int t = tb + j;
        if (t < t1) {
          while (t >= nxt) {   // advance/flush (block-uniform branch)
            z[(long)(base + g) * LD + c] = f2b(s);
            ++g;
            s = b2f(h[(long)(base + g) * LD + c]);
            nxt = indptr[base + g + 1];
          }
          s += (mj > 0.f) ? mj : 0.f;
        }
      }
    }
  }

  // flush the node in flight, then remaining (possibly empty) nodes as h-copy
  z[(long)(base + g) * LD + c] = f2b(s);
  for (++g; g < GNB; ++g) {
    s = b2f(h[(long)(base + g) * LD + c]);
    z[(long)(base + g) * LD + c] = f2b(s);
  }
}

// ---------------------------------------------------------------------------
// pooling: seg sorted -> block b binary-searches node range, no atomics
// ---------------------------------------------------------------------------
__global__ __launch_bounds__(320) void pool_kernel(
    const u16* __restrict__ h, const int* __restrict__ seg, float* __restrict__ acc)
{
  int b = blockIdx.x;
  int lo, hi;
  { int l = 0, r = NN; while (l < r) { int m = (l + r) >> 1; if (seg[m] < b) l = m + 1; else r = m; } lo = l; }
  { int l = lo, r = NN; while (l < r) { int m = (l + r) >> 1; if (seg[m] < b + 1) l = m + 1; else r = m; } hi = l; }
  int j = threadIdx.x;
  if (j < HH) {
    float s = 0.f;
    for (int n = lo; n < hi; ++n) s += b2f(h[(long)n * LD + j]);
    acc[(long)b * HH + j] += s;
  }
}

// out[0:BHSZ) = r - p, where r lives at out[BHSZ..) and p at out[2*BHSZ..)
__global__ __launch_bounds__(256) void combine_kernel(float* __restrict__ out) {
  int i = blockIdx.x * 256 + threadIdx.x;
  if (i < BHSZ) out[i] = out[BHSZ + i] - out[2 * BHSZ + i];
}

// ---------------------------------------------------------------------------
extern "C" void kernel_launch(void* const* d_in, const int* in_sizes, int n_in,
                              void* d_out, int out_size, void* d_ws, size_t ws_size,
                              hipStream_t stream)
{
  (void)in_sizes; (void)n_in; (void)out_size; (void)ws_size;
  const float* r_x = (const float*)d_in[0];
  const float* r_e = (const float*)d_in[1];
  const float* p_x = (const float*)d_in[2];
  const float* p_e = (const float*)d_in[3];
  const float* Wn  = (const float*)d_in[4];
  const float* bn  = (const float*)d_in[5];
  const float* We  = (const float*)d_in[6];
  const float* be  = (const float*)d_in[7];
  const float* W1  = (const float*)d_in[8];
  const float* b1  = (const float*)d_in[9];
  const float* W2  = (const float*)d_in[10];
  const float* b2  = (const float*)d_in[11];
  const int* r_src = (const int*)d_in[12];
  const int* r_dst = (const int*)d_in[13];
  const int* r_seg = (const int*)d_in[14];
  const int* p_src = (const int*)d_in[15];
  const int* p_dst = (const int*)d_in[16];
  const int* p_seg = (const int*)d_in[17];
  float* out = (float*)d_out;

  // --- workspace layout (~163 MB, proven to fit) ---
  char* ws = (char*)d_ws;
  size_t off = 0;
  auto take = [&](size_t bytes) -> char* {
    char* p = ws + off;
    off = (off + bytes + 255) & ~(size_t)255;
    return p;
  };
  u16*   nb0     = (u16*)  take((size_t)NN * LD * 2);       // h / t ping
  u16*   nb1     = (u16*)  take((size_t)NN * LD * 2);       // z / h pong
  u16*   wtAll   = (u16*)  take((size_t)8 * WTSL * 2);      // transposed weights
  float* biasAll = (float*)take((size_t)8 * NCP * 4);       // padded biases
  int*   indptr  = (int*)  take((size_t)(NN + 1) * 4);
  int*   cursor  = (int*)  take((size_t)NN * 4);
  int2*  ess     = (int2*) take((size_t)EE * 8);            // dst-sorted {eid,src}

  float* r_acc = out + BHSZ;       // pooled reactant sums (f32, output 1)
  float* p_acc = out + 2 * BHSZ;   // pooled product sums  (f32, output 2)

  prep_kernel<<<3852, 256, 0, stream>>>(Wn, We, W1, W2, bn, be, b1, b2, wtAll, biasAll);
  zero_kernel<<<2400, 256, 0, stream>>>((float4*)r_acc, 614400);   // r_acc + p_acc

  const float* xs[3] = { r_x, r_x + (size_t)NN * 64, p_x };
  const float* es[3] = { r_e, r_e + (size_t)EE * 16, p_e };
  const int* srcs[3] = { r_src, r_src + EE, p_src };
  const int* dsts[3] = { r_dst, r_dst + EE, p_dst };
  const int* segs[3] = { r_seg, r_seg + NN, p_seg };
  float*     accs[3] = { r_acc, r_acc, p_acc };

  for (int g = 0; g < 3; ++g) {
    // CSR by dst (reused across the 3 layers of this graph)
    zero_kernel<<<120, 256, 0, stream>>>((float4*)cursor, 30720);
    count_kernel<<<960, 256, 0, stream>>>(dsts[g], cursor);
    scan_kernel<<<1, 1024, 0, stream>>>(cursor, indptr);
    fill_kernel<<<960, 256, 0, stream>>>(dsts[g], srcs[g], cursor, ess);

    // h = relu(x @ Wn + bn)   (f32 A, K=64)
    gemm_kernel<<<dim3(NN / 128, 2), 256, 0, stream>>>(xs[g], 64, 64, 1,
        wtAll, biasAll, nb0, 1);

    u16* hA = nb0; u16* hB = nb1;
    for (int l = 0; l < 3; ++l) {
      gather_kernel<<<NN / GNB, 320, 0, stream>>>(hA, es[g], wtAll + WTSL,
          biasAll + NCP, ess, indptr, hB);
      // t = relu(z @ W1[l] + b1[l])
      gemm_kernel<<<dim3(NN / 128, 2), 256, 0, stream>>>(hB, LD, LD, 0,
          wtAll + (2 + l) * WTSL, biasAll + (2 + l) * NCP, hA, 1);
      // h = t @ W2[l] + b2[l]  (+relu if l<2)
      gemm_kernel<<<dim3(NN / 128, 2), 256, 0, stream>>>(hA, LD, LD, 0,
          wtAll + (5 + l) * WTSL, biasAll + (5 + l) * NCP, hB, (l < 2) ? 1 : 0);
      u16* tmp = hA; hA = hB; hB = tmp;
    }
    pool_kernel<<<BB, 320, 0, stream>>>(hA, segs[g], accs[g]);
  }
  combine_kernel<<<4800, 256, 0, stream>>>(out);
}

// Round 5
// 3764.475 us; speedup vs baseline: 1.5044x; 1.5044x over previous
//
#include <hip/hip_runtime.h>

typedef unsigned short u16;
typedef __attribute__((ext_vector_type(8))) short short8;
typedef __attribute__((ext_vector_type(4))) float f32x4;

#define NN 122880   // nodes per graph
#define EE 245760   // edges per graph
#define BB 4096     // reactions
#define HH 300      // hidden
#define LD 320      // padded feature leading dim (mult of 32)
#define NCP 384     // padded out-col count in WT slots
#define WTSL (NCP * LD)   // elements per transposed-weight slot
#define BHSZ (BB * HH)
#define GNB 4       // nodes per gather block (4x more blocks than GNB=16 ->
                    // 4x shorter serial edge chain per block; latency-bound fix)

__device__ __forceinline__ float b2f(u16 s) {
  union { unsigned int u; float f; } v; v.u = ((unsigned int)s) << 16; return v.f;
}
__device__ __forceinline__ u16 f2b(float f) {
  union { float f; unsigned int u; } v; v.f = f;
  unsigned int r = v.u + 0x7FFFu + ((v.u >> 16) & 1u);
  return (u16)(r >> 16);
}

// ---------------------------------------------------------------------------
// prep: f32 weights -> zero-padded transposed bf16 WT[slot][n(384)][k(320)],
// f32 biases -> padded f32 bias[slot][384]. Slots: 0=Wn 1=We 2..4=W1 5..7=W2
// ---------------------------------------------------------------------------
__global__ __launch_bounds__(256) void prep_kernel(
    const float* __restrict__ Wn, const float* __restrict__ We,
    const float* __restrict__ W1, const float* __restrict__ W2,
    const float* __restrict__ bn, const float* __restrict__ be,
    const float* __restrict__ b1, const float* __restrict__ b2,
    u16* __restrict__ wtAll, float* __restrict__ biasAll)
{
  int idx = blockIdx.x * 256 + threadIdx.x;
  if (idx < 8 * WTSL) {
    int slot = idx / WTSL, rem = idx % WTSL;
    int n = rem / LD, k = rem % LD;
    float v = 0.f;
    if (n < HH) {
      if (slot == 0)      { if (k < 64)  v = Wn[k * HH + n]; }
      else if (slot == 1) { if (k < 16)  v = We[k * HH + n]; }
      else if (slot < 5)  { int l = slot - 2; if (k < HH) v = W1[(l * HH + k) * HH + n]; }
      else                { int l = slot - 5; if (k < HH) v = W2[(l * HH + k) * HH + n]; }
    }
    wtAll[idx] = f2b(v);
  } else {
    int j = idx - 8 * WTSL;
    if (j < 8 * NCP) {
      int slot = j / NCP, n = j % NCP;
      float v = 0.f;
      if (n < HH) {
        const float* bp = (slot == 0) ? bn : (slot == 1) ? be
                         : (slot < 5) ? (b1 + (slot - 2) * HH) : (b2 + (slot - 5) * HH);
        v = bp[n];
      }
      biasAll[j] = v;
    }
  }
}

__global__ __launch_bounds__(256) void zero_kernel(float4* __restrict__ p, int n4) {
  int i = blockIdx.x * 256 + threadIdx.x;
  if (i < n4) p[i] = make_float4(0.f, 0.f, 0.f, 0.f);
}

// ---------------------------------------------------------------------------
// CSR build: cursor doubles as counts; scan converts in place.
// fill writes int2{edge id, src id}, dst-sorted.
// ---------------------------------------------------------------------------
__global__ __launch_bounds__(256) void count_kernel(
    const int* __restrict__ dst, int* __restrict__ cursor)
{
  int e = blockIdx.x * 256 + threadIdx.x;
  if (e < EE) atomicAdd(&cursor[dst[e]], 1);
}

__global__ __launch_bounds__(1024) void scan_kernel(
    int* __restrict__ cursor, int* __restrict__ indptr)
{
  __shared__ int sd[1024];
  const int tid = threadIdx.x;
  const int base = tid * 120;          // 1024 * 120 == NN exactly
  int s = 0;
  for (int i = 0; i < 120; ++i) s += cursor[base + i];
  sd[tid] = s;
  __syncthreads();
  for (int off = 1; off < 1024; off <<= 1) {
    int v = (tid >= off) ? sd[tid - off] : 0;
    __syncthreads();
    sd[tid] += v;
    __syncthreads();
  }
  int run = sd[tid] - s;               // exclusive prefix
  for (int i = 0; i < 120; ++i) {
    int c = cursor[base + i];
    indptr[base + i] = run;
    cursor[base + i] = run;
    run += c;
  }
  if (tid == 1023) indptr[NN] = run;   // == EE
}

__global__ __launch_bounds__(256) void fill_kernel(
    const int* __restrict__ dst, const int* __restrict__ src,
    int* __restrict__ cursor, int2* __restrict__ ess)
{
  int e = blockIdx.x * 256 + threadIdx.x;
  if (e < EE) {
    int pos = atomicAdd(&cursor[dst[e]], 1);
    ess[pos] = make_int2(e, src[e]);
  }
}

// ---------------------------------------------------------------------------
// MFMA GEMM: C[r,c] = op(A[r,:K] @ W[:K,c] + bias[c]), bf16 out.
// A bf16 (a_f32=0) or f32 (a_f32=1, converted in staging). WT: [384][320]
// transposed bf16, zero pads. Block tile 128 rows x 160 cols (grid.y=2 covers
// 320 cols; pads 300..319 store exact 0). 4 waves 2x2, wave = 64x80 = 4x5
// MFMA 16x16x32 tiles.
// ---------------------------------------------------------------------------
__global__ __launch_bounds__(256) void gemm_kernel(
    const void* __restrict__ A, int lda, int K, int a_f32,
    const u16* __restrict__ WT, const float* __restrict__ bias,
    u16* __restrict__ C, int relu)
{
  __shared__ u16 As[128][40];   // +8 pad: rows 80B, 16B-aligned chunks
  __shared__ u16 Bs[160][40];

  const int tid = threadIdx.x;
  const int lane = tid & 63, w = tid >> 6;
  const int wm = (w >> 1) * 64, wn = (w & 1) * 80;
  const int m16 = lane & 15, q = lane >> 4;
  const long r0 = (long)blockIdx.x * 128;
  const int c0 = blockIdx.y * 160;

  f32x4 acc[4][5];
#pragma unroll
  for (int i = 0; i < 4; ++i)
#pragma unroll
    for (int j = 0; j < 5; ++j) acc[i][j] = (f32x4){0.f, 0.f, 0.f, 0.f};

  const int nk = K >> 5;
  for (int kt = 0; kt < nk; ++kt) {
    __syncthreads();
    // A tile: 128 rows x 32 k = 512 8-elem chunks
#pragma unroll
    for (int i = 0; i < 2; ++i) {
      int ci = tid + i * 256;
      int row = ci >> 2, kc = (ci & 3) << 3;
      int kg = (kt << 5) + kc;
      if (a_f32) {
        const float* Af = (const float*)A + (r0 + row) * (long)lda + kg;
        float4 v0 = *(const float4*)Af;
        float4 v1 = *(const float4*)(Af + 4);
        ushort4 p0, p1;
        p0.x = f2b(v0.x); p0.y = f2b(v0.y); p0.z = f2b(v0.z); p0.w = f2b(v0.w);
        p1.x = f2b(v1.x); p1.y = f2b(v1.y); p1.z = f2b(v1.z); p1.w = f2b(v1.w);
        *(ushort4*)&As[row][kc] = p0;
        *(ushort4*)&As[row][kc + 4] = p1;
      } else {
        uint4 av = *(const uint4*)((const u16*)A + (r0 + row) * (long)lda + kg);
        *(uint4*)&As[row][kc] = av;
      }
    }
    // B tile: 160 rows x 32 k = 640 chunks
#pragma unroll
    for (int i = 0; i < 3; ++i) {
      int ci = tid + i * 256;
      if (ci < 640) {
        int row = ci >> 2, kc = (ci & 3) << 3;
        int kg = (kt << 5) + kc;
        uint4 bv = *(const uint4*)(WT + (long)(c0 + row) * LD + kg);
        *(uint4*)&Bs[row][kc] = bv;
      }
    }
    __syncthreads();

    short8 af[4], bf[5];
#pragma unroll
    for (int t = 0; t < 4; ++t) af[t] = *(const short8*)&As[wm + t * 16 + m16][q << 3];
#pragma unroll
    for (int t = 0; t < 5; ++t) bf[t] = *(const short8*)&Bs[wn + t * 16 + m16][q << 3];
#pragma unroll
    for (int tm = 0; tm < 4; ++tm)
#pragma unroll
      for (int tn = 0; tn < 5; ++tn)
        acc[tm][tn] = __builtin_amdgcn_mfma_f32_16x16x32_bf16(af[tm], bf[tn], acc[tm][tn], 0, 0, 0);
  }

  // D row = q*4+i, col = lane&15 (m89/m91-verified C/D layout)
#pragma unroll
  for (int tn = 0; tn < 5; ++tn) {
    int c = c0 + wn + tn * 16 + m16;
    float bv = bias[c];
#pragma unroll
    for (int tm = 0; tm < 4; ++tm) {
      long rbase = r0 + wm + tm * 16 + q * 4;
#pragma unroll
      for (int i = 0; i < 4; ++i) {
        float v = acc[tm][tn][i] + bv;
        if (relu) v = v > 0.f ? v : 0.f;
        C[(rbase + i) * LD + c] = f2b(v);
      }
    }
  }
}

// ---------------------------------------------------------------------------
// gather: z[n] = h[n] + sum_{t: dst-sorted edges of n} relu(h[src]+eraw@We+be)
// Each thread owns ONE column (tid == c), register accumulator, no LDS.
// R4 post-mortem: forced inline-asm ILP regressed (406us; volatile chain +
// sched_barrier killed wave concurrency, vmcnt(0) drained its own prefetch).
// This round: keep R3's compiler-scheduled loop but shrink the per-block
// serial edge chain 4x via GNB=4 (30720 blocks, ~8 edges each). Latency is
// hidden by block-level parallelism instead of intra-thread ILP.
// Per-edge math order unchanged (bit-identical numerics).
// Pad cols (300..319) are exactly 0 everywhere -> no guards needed.
// ---------------------------------------------------------------------------
__global__ __launch_bounds__(320) void gather_kernel(
    const u16* __restrict__ h, const float* __restrict__ eraw,
    const u16* __restrict__ wtE, const float* __restrict__ biasE,
    const int2* __restrict__ ess, const int* __restrict__ indptr,
    u16* __restrict__ z)
{
  const int base = blockIdx.x * GNB;
  const int c = threadIdx.x;

  float wreg[16];
  {
    uint4 w0 = *(const uint4*)(wtE + (long)c * LD);
    uint4 w1 = *(const uint4*)(wtE + (long)c * LD + 8);
    const u16* pw0 = (const u16*)&w0;
    const u16* pw1 = (const u16*)&w1;
#pragma unroll
    for (int k = 0; k < 8; ++k) { wreg[k] = b2f(pw0[k]); wreg[8 + k] = b2f(pw1[k]); }
  }
  const float bv = biasE[c];

  const int t0 = indptr[base];
  const int t1 = indptr[base + GNB];

  int g = 0;                              // current node within block
  int nxt = indptr[base + 1];             // end of current node's edge range
  float s = b2f(h[(long)base * LD + c]);  // z = h + agg, eps = 0

  for (int tb = t0; tb < t1; tb += 4) {
    // tail-clamped edge indices (duplicates are guard-skipped below)
    const int tB = (tb + 1 < t1) ? tb + 1 : t1 - 1;
    const int tC = (tb + 2 < t1) ? tb + 2 : t1 - 1;
    const int tD = (tb + 3 < t1) ? tb + 3 : t1 - 1;
    int2 eA = ess[tb], eB = ess[tB], eC = ess[tC], eD = ess[tD];

    const float* rA = eraw + (long)eA.x * 16;
    const float* rB = eraw + (long)eB.x * 16;
    const float* rC = eraw + (long)eC.x * 16;
    const float* rD = eraw + (long)eD.x * 16;
    float4 A0 = *(const float4*)rA, A1 = *(const float4*)(rA + 4),
           A2 = *(const float4*)(rA + 8), A3 = *(const float4*)(rA + 12);
    float4 B0 = *(const float4*)rB, B1 = *(const float4*)(rB + 4),
           B2 = *(const float4*)(rB + 8), B3 = *(const float4*)(rB + 12);
    float4 C0 = *(const float4*)rC, C1 = *(const float4*)(rC + 4),
           C2 = *(const float4*)(rC + 8), C3 = *(const float4*)(rC + 12);
    float4 D0 = *(const float4*)rD, D1 = *(const float4*)(rD + 4),
           D2 = *(const float4*)(rD + 8), D3 = *(const float4*)(rD + 12);
    float hA = b2f(h[(long)eA.y * LD + c]);
    float hB = b2f(h[(long)eB.y * LD + c]);
    float hC = b2f(h[(long)eC.y * LD + c]);
    float hD = b2f(h[(long)eD.y * LD + c]);

    float mA = bv;
    mA += A0.x * wreg[0];  mA += A0.y * wreg[1];  mA += A0.z * wreg[2];  mA += A0.w * wreg[3];
    mA += A1.x * wreg[4];  mA += A1.y * wreg[5];  mA += A1.z * wreg[6];  mA += A1.w * wreg[7];
    mA += A2.x * wreg[8];  mA += A2.y * wreg[9];  mA += A2.z * wreg[10]; mA += A2.w * wreg[11];
    mA += A3.x * wreg[12]; mA += A3.y * wreg[13]; mA += A3.z * wreg[14]; mA += A3.w * wreg[15];
    mA += hA;
    float mB = bv;
    mB += B0.x * wreg[0];  mB += B0.y * wreg[1];  mB += B0.z * wreg[2];  mB += B0.w * wreg[3];
    mB += B1.x * wreg[4];  mB += B1.y * wreg[5];  mB += B1.z * wreg[6];  mB += B1.w * wreg[7];
    mB += B2.x * wreg[8];  mB += B2.y * wreg[9];  mB += B2.z * wreg[10]; mB += B2.w * wreg[11];
    mB += B3.x * wreg[12]; mB += B3.y * wreg[13]; mB += B3.z * wreg[14]; mB += B3.w * wreg[15];
    mB += hB;
    float mC = bv;
    mC += C0.x * wreg[0];  mC += C0.y * wreg[1];  mC += C0.z * wreg[2];  mC += C0.w * wreg[3];
    mC += C1.x * wreg[4];  mC += C1.y * wreg[5];  mC += C1.z * wreg[6];  mC += C1.w * wreg[7];
    mC += C2.x * wreg[8];  mC += C2.y * wreg[9];  mC += C2.z * wreg[10]; mC += C2.w * wreg[11];
    mC += C3.x * wreg[12]; mC += C3.y * wreg[13]; mC += C3.z * wreg[14]; mC += C3.w * wreg[15];
    mC += hC;
    float mD = bv;
    mD += D0.x * wreg[0];  mD += D0.y * wreg[1];  mD += D0.z * wreg[2];  mD += D0.w * wreg[3];
    mD += D1.x * wreg[4];  mD += D1.y * wreg[5];  mD += D1.z * wreg[6];  mD += D1.w * wreg[7];
    mD += D2.x * wreg[8];  mD += D2.y * wreg[9];  mD += D2.z * wreg[10]; mD += D2.w * wreg[11];
    mD += D3.x * wreg[12]; mD += D3.y * wreg[13]; mD += D3.z * wreg[14]; mD += D3.w * wreg[15];
    mD += hD;

#pragma unroll
    for (int j = 0; j < 4; ++j) {
      const float mj = (j == 0) ? mA : (j == 1) ? mB : (j == 2) ? mC : mD;
      const int t = tb + j;
      if (t < t1) {
        while (t >= nxt) {   // advance/flush (block-uniform branch)
          z[(long)(base + g) * LD + c] = f2b(s);
          ++g;
          s = b2f(h[(long)(base + g) * LD + c]);
          nxt = indptr[base + g + 1];
        }
        s += (mj > 0.f) ? mj : 0.f;
      }
    }
  }

  // flush the node in flight, then remaining (possibly empty) nodes as h-copy
  z[(long)(base + g) * LD + c] = f2b(s);
  for (++g; g < GNB; ++g) {
    s = b2f(h[(long)(base + g) * LD + c]);
    z[(long)(base + g) * LD + c] = f2b(s);
  }
}

// ---------------------------------------------------------------------------
// pooling: seg sorted -> block b binary-searches node range, no atomics
// ---------------------------------------------------------------------------
__global__ __launch_bounds__(320) void pool_kernel(
    const u16* __restrict__ h, const int* __restrict__ seg, float* __restrict__ acc)
{
  int b = blockIdx.x;
  int lo, hi;
  { int l = 0, r = NN; while (l < r) { int m = (l + r) >> 1; if (seg[m] < b) l = m + 1; else r = m; } lo = l; }
  { int l = lo, r = NN; while (l < r) { int m = (l + r) >> 1; if (seg[m] < b + 1) l = m + 1; else r = m; } hi = l; }
  int j = threadIdx.x;
  if (j < HH) {
    float s = 0.f;
    for (int n = lo; n < hi; ++n) s += b2f(h[(long)n * LD + j]);
    acc[(long)b * HH + j] += s;
  }
}

// out[0:BHSZ) = r - p, where r lives at out[BHSZ..) and p at out[2*BHSZ..)
__global__ __launch_bounds__(256) void combine_kernel(float* __restrict__ out) {
  int i = blockIdx.x * 256 + threadIdx.x;
  if (i < BHSZ) out[i] = out[BHSZ + i] - out[2 * BHSZ + i];
}

// ---------------------------------------------------------------------------
extern "C" void kernel_launch(void* const* d_in, const int* in_sizes, int n_in,
                              void* d_out, int out_size, void* d_ws, size_t ws_size,
                              hipStream_t stream)
{
  (void)in_sizes; (void)n_in; (void)out_size; (void)ws_size;
  const float* r_x = (const float*)d_in[0];
  const float* r_e = (const float*)d_in[1];
  const float* p_x = (const float*)d_in[2];
  const float* p_e = (const float*)d_in[3];
  const float* Wn  = (const float*)d_in[4];
  const float* bn  = (const float*)d_in[5];
  const float* We  = (const float*)d_in[6];
  const float* be  = (const float*)d_in[7];
  const float* W1  = (const float*)d_in[8];
  const float* b1  = (const float*)d_in[9];
  const float* W2  = (const float*)d_in[10];
  const float* b2  = (const float*)d_in[11];
  const int* r_src = (const int*)d_in[12];
  const int* r_dst = (const int*)d_in[13];
  const int* r_seg = (const int*)d_in[14];
  const int* p_src = (const int*)d_in[15];
  const int* p_dst = (const int*)d_in[16];
  const int* p_seg = (const int*)d_in[17];
  float* out = (float*)d_out;

  // --- workspace layout (~163 MB, proven to fit) ---
  char* ws = (char*)d_ws;
  size_t off = 0;
  auto take = [&](size_t bytes) -> char* {
    char* p = ws + off;
    off = (off + bytes + 255) & ~(size_t)255;
    return p;
  };
  u16*   nb0     = (u16*)  take((size_t)NN * LD * 2);       // h / t ping
  u16*   nb1     = (u16*)  take((size_t)NN * LD * 2);       // z / h pong
  u16*   wtAll   = (u16*)  take((size_t)8 * WTSL * 2);      // transposed weights
  float* biasAll = (float*)take((size_t)8 * NCP * 4);       // padded biases
  int*   indptr  = (int*)  take((size_t)(NN + 1) * 4);
  int*   cursor  = (int*)  take((size_t)NN * 4);
  int2*  ess     = (int2*) take((size_t)EE * 8);            // dst-sorted {eid,src}

  float* r_acc = out + BHSZ;       // pooled reactant sums (f32, output 1)
  float* p_acc = out + 2 * BHSZ;   // pooled product sums  (f32, output 2)

  prep_kernel<<<3852, 256, 0, stream>>>(Wn, We, W1, W2, bn, be, b1, b2, wtAll, biasAll);
  zero_kernel<<<2400, 256, 0, stream>>>((float4*)r_acc, 614400);   // r_acc + p_acc

  const float* xs[3] = { r_x, r_x + (size_t)NN * 64, p_x };
  const float* es[3] = { r_e, r_e + (size_t)EE * 16, p_e };
  const int* srcs[3] = { r_src, r_src + EE, p_src };
  const int* dsts[3] = { r_dst, r_dst + EE, p_dst };
  const int* segs[3] = { r_seg, r_seg + NN, p_seg };
  float*     accs[3] = { r_acc, r_acc, p_acc };

  for (int g = 0; g < 3; ++g) {
    // CSR by dst (reused across the 3 layers of this graph)
    zero_kernel<<<120, 256, 0, stream>>>((float4*)cursor, 30720);
    count_kernel<<<960, 256, 0, stream>>>(dsts[g], cursor);
    scan_kernel<<<1, 1024, 0, stream>>>(cursor, indptr);
    fill_kernel<<<960, 256, 0, stream>>>(dsts[g], srcs[g], cursor, ess);

    // h = relu(x @ Wn + bn)   (f32 A, K=64)
    gemm_kernel<<<dim3(NN / 128, 2), 256, 0, stream>>>(xs[g], 64, 64, 1,
        wtAll, biasAll, nb0, 1);

    u16* hA = nb0; u16* hB = nb1;
    for (int l = 0; l < 3; ++l) {
      gather_kernel<<<NN / GNB, 320, 0, stream>>>(hA, es[g], wtAll + WTSL,
          biasAll + NCP, ess, indptr, hB);
      // t = relu(z @ W1[l] + b1[l])
      gemm_kernel<<<dim3(NN / 128, 2), 256, 0, stream>>>(hB, LD, LD, 0,
          wtAll + (2 + l) * WTSL, biasAll + (2 + l) * NCP, hA, 1);
      // h = t @ W2[l] + b2[l]  (+relu if l<2)
      gemm_kernel<<<dim3(NN / 128, 2), 256, 0, stream>>>(hA, LD, LD, 0,
          wtAll + (5 + l) * WTSL, biasAll + (5 + l) * NCP, hB, (l < 2) ? 1 : 0);
      u16* tmp = hA; hA = hB; hB = tmp;
    }
    pool_kernel<<<BB, 320, 0, stream>>>(hA, segs[g], accs[g]);
  }
  combine_kernel<<<4800, 256, 0, stream>>>(out);
}

// Round 7
// 3746.897 us; speedup vs baseline: 1.5115x; 1.0047x over previous
//
#include <hip/hip_runtime.h>

typedef unsigned short u16;
typedef __attribute__((ext_vector_type(8))) short short8;
typedef __attribute__((ext_vector_type(4))) float f32x4;

#define NN 122880   // nodes per graph
#define EE 245760   // edges per graph
#define BB 4096     // reactions
#define HH 300      // hidden
#define LD 320      // padded feature leading dim (mult of 32)
#define NCP 384     // padded out-col count in WT slots
#define WTSL (NCP * LD)   // elements per transposed-weight slot
#define BHSZ (BB * HH)
#define GNB 16      // nodes per gather block (R3 best config: 160us)

__device__ __forceinline__ float b2f(u16 s) {
  union { unsigned int u; float f; } v; v.u = ((unsigned int)s) << 16; return v.f;
}
__device__ __forceinline__ u16 f2b(float f) {
  union { float f; unsigned int u; } v; v.f = f;
  unsigned int r = v.u + 0x7FFFu + ((v.u >> 16) & 1u);
  return (u16)(r >> 16);
}

// ---------------------------------------------------------------------------
// prep: f32 weights -> zero-padded transposed bf16 WT[slot][n(384)][k(320)],
// f32 biases -> padded f32 bias[slot][384]. Slots: 0=Wn 1=We 2..4=W1 5..7=W2
// ---------------------------------------------------------------------------
__global__ __launch_bounds__(256) void prep_kernel(
    const float* __restrict__ Wn, const float* __restrict__ We,
    const float* __restrict__ W1, const float* __restrict__ W2,
    const float* __restrict__ bn, const float* __restrict__ be,
    const float* __restrict__ b1, const float* __restrict__ b2,
    u16* __restrict__ wtAll, float* __restrict__ biasAll)
{
  int idx = blockIdx.x * 256 + threadIdx.x;
  if (idx < 8 * WTSL) {
    int slot = idx / WTSL, rem = idx % WTSL;
    int n = rem / LD, k = rem % LD;
    float v = 0.f;
    if (n < HH) {
      if (slot == 0)      { if (k < 64)  v = Wn[k * HH + n]; }
      else if (slot == 1) { if (k < 16)  v = We[k * HH + n]; }
      else if (slot < 5)  { int l = slot - 2; if (k < HH) v = W1[(l * HH + k) * HH + n]; }
      else                { int l = slot - 5; if (k < HH) v = W2[(l * HH + k) * HH + n]; }
    }
    wtAll[idx] = f2b(v);
  } else {
    int j = idx - 8 * WTSL;
    if (j < 8 * NCP) {
      int slot = j / NCP, n = j % NCP;
      float v = 0.f;
      if (n < HH) {
        const float* bp = (slot == 0) ? bn : (slot == 1) ? be
                         : (slot < 5) ? (b1 + (slot - 2) * HH) : (b2 + (slot - 5) * HH);
        v = bp[n];
      }
      biasAll[j] = v;
    }
  }
}

__global__ __launch_bounds__(256) void zero_kernel(float4* __restrict__ p, int n4) {
  int i = blockIdx.x * 256 + threadIdx.x;
  if (i < n4) p[i] = make_float4(0.f, 0.f, 0.f, 0.f);
}

// ---------------------------------------------------------------------------
// CSR build: cursor doubles as counts; scan converts in place.
// fill writes int2{edge id, src id}, dst-sorted.
// ---------------------------------------------------------------------------
__global__ __launch_bounds__(256) void count_kernel(
    const int* __restrict__ dst, int* __restrict__ cursor)
{
  int e = blockIdx.x * 256 + threadIdx.x;
  if (e < EE) atomicAdd(&cursor[dst[e]], 1);
}

__global__ __launch_bounds__(1024) void scan_kernel(
    int* __restrict__ cursor, int* __restrict__ indptr)
{
  __shared__ int sd[1024];
  const int tid = threadIdx.x;
  const int base = tid * 120;          // 1024 * 120 == NN exactly
  int s = 0;
  for (int i = 0; i < 120; ++i) s += cursor[base + i];
  sd[tid] = s;
  __syncthreads();
  for (int off = 1; off < 1024; off <<= 1) {
    int v = (tid >= off) ? sd[tid - off] : 0;
    __syncthreads();
    sd[tid] += v;
    __syncthreads();
  }
  int run = sd[tid] - s;               // exclusive prefix
  for (int i = 0; i < 120; ++i) {
    int c = cursor[base + i];
    indptr[base + i] = run;
    cursor[base + i] = run;
    run += c;
  }
  if (tid == 1023) indptr[NN] = run;   // == EE
}

__global__ __launch_bounds__(256) void fill_kernel(
    const int* __restrict__ dst, const int* __restrict__ src,
    int* __restrict__ cursor, int2* __restrict__ ess)
{
  int e = blockIdx.x * 256 + threadIdx.x;
  if (e < EE) {
    int pos = atomicAdd(&cursor[dst[e]], 1);
    ess[pos] = make_int2(e, src[e]);
  }
}

// ---------------------------------------------------------------------------
// MFMA GEMM, LDS-FREE: C[r,c] = op(A[r,:K] @ W[:K,c] + bias[c]), bf16 out.
// Key observation: both operands' MFMA fragments are CONTIGUOUS 16B runs in
// global memory (A row-major k-contiguous; WT pre-transposed [outcol][k],
// L2-resident 240KB). So each lane loads its fragment directly from global:
// no LDS, no __syncthreads, no per-ktile vmcnt(0)+lgkmcnt(0) barrier drain
// (the m97-structure stall). Compiler pipelines kt+1 fragment loads under
// kt's 20 MFMAs freely. Block tile 128 rows x 160 cols (grid.y=2), 4 waves
// 2x2, wave = 64x80 = 4x5 MFMA 16x16x32 tiles. Accumulation order per kt
// unchanged -> bit-identical numerics vs LDS version.
// ---------------------------------------------------------------------------
__global__ __launch_bounds__(256, 2) void gemm_kernel(
    const void* __restrict__ A, int lda, int K, int a_f32,
    const u16* __restrict__ WT, const float* __restrict__ bias,
    u16* __restrict__ C, int relu)
{
  const int tid = threadIdx.x;
  const int lane = tid & 63, w = tid >> 6;
  const int wm = (w >> 1) * 64, wn = (w & 1) * 80;
  const int m16 = lane & 15, q = lane >> 4;
  const long r0 = (long)blockIdx.x * 128;
  const int c0 = blockIdx.y * 160;

  f32x4 acc[4][5];
#pragma unroll
  for (int i = 0; i < 4; ++i)
#pragma unroll
    for (int j = 0; j < 5; ++j) acc[i][j] = (f32x4){0.f, 0.f, 0.f, 0.f};

  const int nk = K >> 5;
  // B fragment base: row (c0+wn+t*16+m16) of WT, k-offset q*8  (16B runs)
  const u16* Bb = WT + (long)(c0 + wn + m16) * LD + (q << 3);

  if (a_f32) {
    const float* Ab = (const float*)A + (r0 + wm + m16) * (long)lda + (q << 3);
#pragma unroll
    for (int kt = 0; kt < 2; ++kt) {      // K=64 path: exactly 2 ktiles
      const int kg = kt << 5;
      short8 af[4], bf[5];
#pragma unroll
      for (int t = 0; t < 4; ++t) {
        const float* ap = Ab + (long)t * 16 * lda + kg;
        float4 v0 = *(const float4*)ap;
        float4 v1 = *(const float4*)(ap + 4);
        short8 r;
        r[0] = (short)f2b(v0.x); r[1] = (short)f2b(v0.y);
        r[2] = (short)f2b(v0.z); r[3] = (short)f2b(v0.w);
        r[4] = (short)f2b(v1.x); r[5] = (short)f2b(v1.y);
        r[6] = (short)f2b(v1.z); r[7] = (short)f2b(v1.w);
        af[t] = r;
      }
#pragma unroll
      for (int t = 0; t < 5; ++t) bf[t] = *(const short8*)(Bb + (long)t * 16 * LD + kg);
#pragma unroll
      for (int tm = 0; tm < 4; ++tm)
#pragma unroll
        for (int tn = 0; tn < 5; ++tn)
          acc[tm][tn] = __builtin_amdgcn_mfma_f32_16x16x32_bf16(af[tm], bf[tn], acc[tm][tn], 0, 0, 0);
    }
  } else {
    const u16* Ab = (const u16*)A + (r0 + wm + m16) * (long)lda + (q << 3);
#pragma unroll 2
    for (int kt = 0; kt < nk; ++kt) {
      const int kg = kt << 5;
      short8 af[4], bf[5];
#pragma unroll
      for (int t = 0; t < 4; ++t) af[t] = *(const short8*)(Ab + (long)t * 16 * lda + kg);
#pragma unroll
      for (int t = 0; t < 5; ++t) bf[t] = *(const short8*)(Bb + (long)t * 16 * LD + kg);
#pragma unroll
      for (int tm = 0; tm < 4; ++tm)
#pragma unroll
        for (int tn = 0; tn < 5; ++tn)
          acc[tm][tn] = __builtin_amdgcn_mfma_f32_16x16x32_bf16(af[tm], bf[tn], acc[tm][tn], 0, 0, 0);
    }
  }

  // D row = q*4+i, col = lane&15 (m89/m91-verified C/D layout)
#pragma unroll
  for (int tn = 0; tn < 5; ++tn) {
    int c = c0 + wn + tn * 16 + m16;
    float bv = bias[c];
#pragma unroll
    for (int tm = 0; tm < 4; ++tm) {
      long rbase = r0 + wm + tm * 16 + q * 4;
#pragma unroll
      for (int i = 0; i < 4; ++i) {
        float v = acc[tm][tn][i] + bv;
        if (relu) v = v > 0.f ? v : 0.f;
        C[(rbase + i) * LD + c] = f2b(v);
      }
    }
  }
}

// ---------------------------------------------------------------------------
// gather: z[n] = h[n] + sum_{t: dst-sorted edges of n} relu(h[src]+eraw@We+be)
// R3 config (best measured: 160us). Thread owns one column; register
// accumulator; no LDS; 4-edge software batch (compiler-scheduled).
// Per-edge math order unchanged (bit-identical numerics).
// Pad cols (300..319) are exactly 0 everywhere -> no guards needed.
// ---------------------------------------------------------------------------
__global__ __launch_bounds__(320) void gather_kernel(
    const u16* __restrict__ h, const float* __restrict__ eraw,
    const u16* __restrict__ wtE, const float* __restrict__ biasE,
    const int2* __restrict__ ess, const int* __restrict__ indptr,
    u16* __restrict__ z)
{
  const int base = blockIdx.x * GNB;
  const int c = threadIdx.x;

  float wreg[16];
  {
    uint4 w0 = *(const uint4*)(wtE + (long)c * LD);
    uint4 w1 = *(const uint4*)(wtE + (long)c * LD + 8);
    const u16* pw0 = (const u16*)&w0;
    const u16* pw1 = (const u16*)&w1;
#pragma unroll
    for (int k = 0; k < 8; ++k) { wreg[k] = b2f(pw0[k]); wreg[8 + k] = b2f(pw1[k]); }
  }
  const float bv = biasE[c];

  const int t0 = indptr[base];
  const int t1 = indptr[base + GNB];

  int g = 0;                              // current node within block
  int nxt = indptr[base + 1];             // end of current node's edge range
  float s = b2f(h[(long)base * LD + c]);  // z = h + agg, eps = 0

  for (int tb = t0; tb < t1; tb += 4) {
    // tail-clamped edge indices (duplicates are guard-skipped below)
    const int tB = (tb + 1 < t1) ? tb + 1 : t1 - 1;
    const int tC = (tb + 2 < t1) ? tb + 2 : t1 - 1;
    const int tD = (tb + 3 < t1) ? tb + 3 : t1 - 1;
    int2 eA = ess[tb], eB = ess[tB], eC = ess[tC], eD = ess[tD];

    const float* rA = eraw + (long)eA.x * 16;
    const float* rB = eraw + (long)eB.x * 16;
    const float* rC = eraw + (long)eC.x * 16;
    const float* rD = eraw + (long)eD.x * 16;
    float4 A0 = *(const float4*)rA, A1 = *(const float4*)(rA + 4),
           A2 = *(const float4*)(rA + 8), A3 = *(const float4*)(rA + 12);
    float4 B0 = *(const float4*)rB, B1 = *(const float4*)(rB + 4),
           B2 = *(const float4*)(rB + 8), B3 = *(const float4*)(rB + 12);
    float4 C0 = *(const float4*)rC, C1 = *(const float4*)(rC + 4),
           C2 = *(const float4*)(rC + 8), C3 = *(const float4*)(rC + 12);
    float4 D0 = *(const float4*)rD, D1 = *(const float4*)(rD + 4),
           D2 = *(const float4*)(rD + 8), D3 = *(const float4*)(rD + 12);
    float hA = b2f(h[(long)eA.y * LD + c]);
    float hB = b2f(h[(long)eB.y * LD + c]);
    float hC = b2f(h[(long)eC.y * LD + c]);
    float hD = b2f(h[(long)eD.y * LD + c]);

    float mA = bv;
    mA += A0.x * wreg[0];  mA += A0.y * wreg[1];  mA += A0.z * wreg[2];  mA += A0.w * wreg[3];
    mA += A1.x * wreg[4];  mA += A1.y * wreg[5];  mA += A1.z * wreg[6];  mA += A1.w * wreg[7];
    mA += A2.x * wreg[8];  mA += A2.y * wreg[9];  mA += A2.z * wreg[10]; mA += A2.w * wreg[11];
    mA += A3.x * wreg[12]; mA += A3.y * wreg[13]; mA += A3.z * wreg[14]; mA += A3.w * wreg[15];
    mA += hA;
    float mB = bv;
    mB += B0.x * wreg[0];  mB += B0.y * wreg[1];  mB += B0.z * wreg[2];  mB += B0.w * wreg[3];
    mB += B1.x * wreg[4];  mB += B1.y * wreg[5];  mB += B1.z * wreg[6];  mB += B1.w * wreg[7];
    mB += B2.x * wreg[8];  mB += B2.y * wreg[9];  mB += B2.z * wreg[10]; mB += B2.w * wreg[11];
    mB += B3.x * wreg[12]; mB += B3.y * wreg[13]; mB += B3.z * wreg[14]; mB += B3.w * wreg[15];
    mB += hB;
    float mC = bv;
    mC += C0.x * wreg[0];  mC += C0.y * wreg[1];  mC += C0.z * wreg[2];  mC += C0.w * wreg[3];
    mC += C1.x * wreg[4];  mC += C1.y * wreg[5];  mC += C1.z * wreg[6];  mC += C1.w * wreg[7];
    mC += C2.x * wreg[8];  mC += C2.y * wreg[9];  mC += C2.z * wreg[10]; mC += C2.w * wreg[11];
    mC += C3.x * wreg[12]; mC += C3.y * wreg[13]; mC += C3.z * wreg[14]; mC += C3.w * wreg[15];
    mC += hC;
    float mD = bv;
    mD += D0.x * wreg[0];  mD += D0.y * wreg[1];  mD += D0.z * wreg[2];  mD += D0.w * wreg[3];
    mD += D1.x * wreg[4];  mD += D1.y * wreg[5];  mD += D1.z * wreg[6];  mD += D1.w * wreg[7];
    mD += D2.x * wreg[8];  mD += D2.y * wreg[9];  mD += D2.z * wreg[10]; mD += D2.w * wreg[11];
    mD += D3.x * wreg[12]; mD += D3.y * wreg[13]; mD += D3.z * wreg[14]; mD += D3.w * wreg[15];
    mD += hD;

#pragma unroll
    for (int j = 0; j < 4; ++j) {
      const float mj = (j == 0) ? mA : (j == 1) ? mB : (j == 2) ? mC : mD;
      const int t = tb + j;
      if (t < t1) {
        while (t >= nxt) {   // advance/flush (block-uniform branch)
          z[(long)(base + g) * LD + c] = f2b(s);
          ++g;
          s = b2f(h[(long)(base + g) * LD + c]);
          nxt = indptr[base + g + 1];
        }
        s += (mj > 0.f) ? mj : 0.f;
      }
    }
  }

  // flush the node in flight, then remaining (possibly empty) nodes as h-copy
  z[(long)(base + g) * LD + c] = f2b(s);
  for (++g; g < GNB; ++g) {
    s = b2f(h[(long)(base + g) * LD + c]);
    z[(long)(base + g) * LD + c] = f2b(s);
  }
}

// ---------------------------------------------------------------------------
// pooling: seg sorted -> block b binary-searches node range, no atomics
// ---------------------------------------------------------------------------
__global__ __launch_bounds__(320) void pool_kernel(
    const u16* __restrict__ h, const int* __restrict__ seg, float* __restrict__ acc)
{
  int b = blockIdx.x;
  int lo, hi;
  { int l = 0, r = NN; while (l < r) { int m = (l + r) >> 1; if (seg[m] < b) l = m + 1; else r = m; } lo = l; }
  { int l = lo, r = NN; while (l < r) { int m = (l + r) >> 1; if (seg[m] < b + 1) l = m + 1; else r = m; } hi = l; }
  int j = threadIdx.x;
  if (j < HH) {
    float s = 0.f;
    for (int n = lo; n < hi; ++n) s += b2f(h[(long)n * LD + j]);
    acc[(long)b * HH + j] += s;
  }
}

// out[0:BHSZ) = r - p, where r lives at out[BHSZ..) and p at out[2*BHSZ..)
__global__ __launch_bounds__(256) void combine_kernel(float* __restrict__ out) {
  int i = blockIdx.x * 256 + threadIdx.x;
  if (i < BHSZ) out[i] = out[BHSZ + i] - out[2 * BHSZ + i];
}

// ---------------------------------------------------------------------------
extern "C" void kernel_launch(void* const* d_in, const int* in_sizes, int n_in,
                              void* d_out, int out_size, void* d_ws, size_t ws_size,
                              hipStream_t stream)
{
  (void)in_sizes; (void)n_in; (void)out_size; (void)ws_size;
  const float* r_x = (const float*)d_in[0];
  const float* r_e = (const float*)d_in[1];
  const float* p_x = (const float*)d_in[2];
  const float* p_e = (const float*)d_in[3];
  const float* Wn  = (const float*)d_in[4];
  const float* bn  = (const float*)d_in[5];
  const float* We  = (const float*)d_in[6];
  const float* be  = (const float*)d_in[7];
  const float* W1  = (const float*)d_in[8];
  const float* b1  = (const float*)d_in[9];
  const float* W2  = (const float*)d_in[10];
  const float* b2  = (const float*)d_in[11];
  const int* r_src = (const int*)d_in[12];
  const int* r_dst = (const int*)d_in[13];
  const int* r_seg = (const int*)d_in[14];
  const int* p_src = (const int*)d_in[15];
  const int* p_dst = (const int*)d_in[16];
  const int* p_seg = (const int*)d_in[17];
  float* out = (float*)d_out;

  // --- workspace layout (~163 MB, proven to fit) ---
  char* ws = (char*)d_ws;
  size_t off = 0;
  auto take = [&](size_t bytes) -> char* {
    char* p = ws + off;
    off = (off + bytes + 255) & ~(size_t)255;
    return p;
  };
  u16*   nb0     = (u16*)  take((size_t)NN * LD * 2);       // h / t ping
  u16*   nb1     = (u16*)  take((size_t)NN * LD * 2);       // z / h pong
  u16*   wtAll   = (u16*)  take((size_t)8 * WTSL * 2);      // transposed weights
  float* biasAll = (float*)take((size_t)8 * NCP * 4);       // padded biases
  int*   indptr  = (int*)  take((size_t)(NN + 1) * 4);
  int*   cursor  = (int*)  take((size_t)NN * 4);
  int2*  ess     = (int2*) take((size_t)EE * 8);            // dst-sorted {eid,src}

  float* r_acc = out + BHSZ;       // pooled reactant sums (f32, output 1)
  float* p_acc = out + 2 * BHSZ;   // pooled product sums  (f32, output 2)

  prep_kernel<<<3852, 256, 0, stream>>>(Wn, We, W1, W2, bn, be, b1, b2, wtAll, biasAll);
  zero_kernel<<<2400, 256, 0, stream>>>((float4*)r_acc, 614400);   // r_acc + p_acc

  const float* xs[3] = { r_x, r_x + (size_t)NN * 64, p_x };
  const float* es[3] = { r_e, r_e + (size_t)EE * 16, p_e };
  const int* srcs[3] = { r_src, r_src + EE, p_src };
  const int* dsts[3] = { r_dst, r_dst + EE, p_dst };
  const int* segs[3] = { r_seg, r_seg + NN, p_seg };
  float*     accs[3] = { r_acc, r_acc, p_acc };

  for (int g = 0; g < 3; ++g) {
    // CSR by dst (reused across the 3 layers of this graph)
    zero_kernel<<<120, 256, 0, stream>>>((float4*)cursor, 30720);
    count_kernel<<<960, 256, 0, stream>>>(dsts[g], cursor);
    scan_kernel<<<1, 1024, 0, stream>>>(cursor, indptr);
    fill_kernel<<<960, 256, 0, stream>>>(dsts[g], srcs[g], cursor, ess);

    // h = relu(x @ Wn + bn)   (f32 A, K=64)
    gemm_kernel<<<dim3(NN / 128, 2), 256, 0, stream>>>(xs[g], 64, 64, 1,
        wtAll, biasAll, nb0, 1);

    u16* hA = nb0; u16* hB = nb1;
    for (int l = 0; l < 3; ++l) {
      gather_kernel<<<NN / GNB, 320, 0, stream>>>(hA, es[g], wtAll + WTSL,
          biasAll + NCP, ess, indptr, hB);
      // t = relu(z @ W1[l] + b1[l])
      gemm_kernel<<<dim3(NN / 128, 2), 256, 0, stream>>>(hB, LD, LD, 0,
          wtAll + (2 + l) * WTSL, biasAll + (2 + l) * NCP, hA, 1);
      // h = t @ W2[l] + b2[l]  (+relu if l<2)
      gemm_kernel<<<dim3(NN / 128, 2), 256, 0, stream>>>(hA, LD, LD, 0,
          wtAll + (5 + l) * WTSL, biasAll + (5 + l) * NCP, hB, (l < 2) ? 1 : 0);
      u16* tmp = hA; hA = hB; hB = tmp;
    }
    pool_kernel<<<BB, 320, 0, stream>>>(hA, segs[g], accs[g]);
  }
  combine_kernel<<<4800, 256, 0, stream>>>(out);
}

// Round 8
// 2952.372 us; speedup vs baseline: 1.9182x; 1.2691x over previous
//
#include <hip/hip_runtime.h>

typedef unsigned short u16;
typedef __attribute__((ext_vector_type(8))) short short8;
typedef __attribute__((ext_vector_type(4))) float f32x4;

#define NN 122880   // nodes per graph
#define EE 245760   // edges per graph
#define BB 4096     // reactions
#define HH 300      // hidden
#define LD 320      // padded feature leading dim (mult of 32)
#define NCP 384     // padded out-col count in WT slots
#define WTSL (NCP * LD)   // elements per transposed-weight slot
#define BHSZ (BB * HH)
#define GNB 16      // nodes per gather block (best measured config: ~158us)

__device__ __forceinline__ float b2f(u16 s) {
  union { unsigned int u; float f; } v; v.u = ((unsigned int)s) << 16; return v.f;
}
__device__ __forceinline__ u16 f2b(float f) {
  union { float f; unsigned int u; } v; v.f = f;
  unsigned int r = v.u + 0x7FFFu + ((v.u >> 16) & 1u);
  return (u16)(r >> 16);
}

// async global->LDS, 16B per lane; LDS dest = wave-uniform base + lane*16
#define GLDS16(gp, lp) __builtin_amdgcn_global_load_lds( \
    (const __attribute__((address_space(1))) unsigned int*)(gp), \
    (__attribute__((address_space(3))) unsigned int*)(lp), 16, 0, 0)

// ---------------------------------------------------------------------------
// prep: f32 weights -> zero-padded transposed bf16 WT[slot][n(384)][k(320)],
// f32 biases -> padded f32 bias[slot][384]. Slots: 0=Wn 1=We 2..4=W1 5..7=W2
// ---------------------------------------------------------------------------
__global__ __launch_bounds__(256) void prep_kernel(
    const float* __restrict__ Wn, const float* __restrict__ We,
    const float* __restrict__ W1, const float* __restrict__ W2,
    const float* __restrict__ bn, const float* __restrict__ be,
    const float* __restrict__ b1, const float* __restrict__ b2,
    u16* __restrict__ wtAll, float* __restrict__ biasAll)
{
  int idx = blockIdx.x * 256 + threadIdx.x;
  if (idx < 8 * WTSL) {
    int slot = idx / WTSL, rem = idx % WTSL;
    int n = rem / LD, k = rem % LD;
    float v = 0.f;
    if (n < HH) {
      if (slot == 0)      { if (k < 64)  v = Wn[k * HH + n]; }
      else if (slot == 1) { if (k < 16)  v = We[k * HH + n]; }
      else if (slot < 5)  { int l = slot - 2; if (k < HH) v = W1[(l * HH + k) * HH + n]; }
      else                { int l = slot - 5; if (k < HH) v = W2[(l * HH + k) * HH + n]; }
    }
    wtAll[idx] = f2b(v);
  } else {
    int j = idx - 8 * WTSL;
    if (j < 8 * NCP) {
      int slot = j / NCP, n = j % NCP;
      float v = 0.f;
      if (n < HH) {
        const float* bp = (slot == 0) ? bn : (slot == 1) ? be
                         : (slot < 5) ? (b1 + (slot - 2) * HH) : (b2 + (slot - 5) * HH);
        v = bp[n];
      }
      biasAll[j] = v;
    }
  }
}

__global__ __launch_bounds__(256) void zero_kernel(float4* __restrict__ p, int n4) {
  int i = blockIdx.x * 256 + threadIdx.x;
  if (i < n4) p[i] = make_float4(0.f, 0.f, 0.f, 0.f);
}

// ---------------------------------------------------------------------------
// CSR build: cursor doubles as counts; scan converts in place.
// fill writes int2{edge id, src id}, dst-sorted.
// ---------------------------------------------------------------------------
__global__ __launch_bounds__(256) void count_kernel(
    const int* __restrict__ dst, int* __restrict__ cursor)
{
  int e = blockIdx.x * 256 + threadIdx.x;
  if (e < EE) atomicAdd(&cursor[dst[e]], 1);
}

__global__ __launch_bounds__(1024) void scan_kernel(
    int* __restrict__ cursor, int* __restrict__ indptr)
{
  __shared__ int sd[1024];
  const int tid = threadIdx.x;
  const int base = tid * 120;          // 1024 * 120 == NN exactly
  int s = 0;
  for (int i = 0; i < 120; ++i) s += cursor[base + i];
  sd[tid] = s;
  __syncthreads();
  for (int off = 1; off < 1024; off <<= 1) {
    int v = (tid >= off) ? sd[tid - off] : 0;
    __syncthreads();
    sd[tid] += v;
    __syncthreads();
  }
  int run = sd[tid] - s;               // exclusive prefix
  for (int i = 0; i < 120; ++i) {
    int c = cursor[base + i];
    indptr[base + i] = run;
    cursor[base + i] = run;
    run += c;
  }
  if (tid == 1023) indptr[NN] = run;   // == EE
}

__global__ __launch_bounds__(256) void fill_kernel(
    const int* __restrict__ dst, const int* __restrict__ src,
    int* __restrict__ cursor, int2* __restrict__ ess)
{
  int e = blockIdx.x * 256 + threadIdx.x;
  if (e < EE) {
    int pos = atomicAdd(&cursor[dst[e]], 1);
    ess[pos] = make_int2(e, src[e]);
  }
}

// ---------------------------------------------------------------------------
// MFMA GEMM: C[r,c] = op(A[r,:K] @ W[:K,c] + bias[c]), bf16 out.
// R7 post-mortem: LDS-free direct fragments regressed (16 strided cache
// lines per VMEM instr, L2 latency per kt). Back to staged LDS, but staging
// now uses global_load_lds width=16 (m151: +35% over reg-staging at 128^2).
// LDS is LINEAR (gload_lds writes base+lane*16; no padding possible):
// chunk (row,q) at byte offset row*64 + q*16. Tile 128x160, grid.y=2,
// 4 waves 2x2, wave = 4x5 MFMA 16x16x32. f32-A path (K=64, 3 launches)
// reg-stages with conversion into the same linear layout.
// Fragment values and MFMA order identical to the R3 kernel.
// ---------------------------------------------------------------------------
__global__ __launch_bounds__(256) void gemm_kernel(
    const void* __restrict__ A, int lda, int K, int a_f32,
    const u16* __restrict__ WT, const float* __restrict__ bias,
    u16* __restrict__ C, int relu)
{
  __shared__ u16 As[128 * 32];   // 16 KB, linear
  __shared__ u16 Bs[160 * 32];   // 10 KB, linear

  const int tid = threadIdx.x;
  const int lane = tid & 63, w = tid >> 6;
  const int wm = (w >> 1) * 64, wn = (w & 1) * 80;
  const int m16 = lane & 15, q = lane >> 4;
  const long r0 = (long)blockIdx.x * 128;
  const int c0 = blockIdx.y * 160;
  const int wavebase = tid & 0xC0;     // wave-uniform lane-group base (chunks)

  f32x4 acc[4][5];
#pragma unroll
  for (int i = 0; i < 4; ++i)
#pragma unroll
    for (int j = 0; j < 5; ++j) acc[i][j] = (f32x4){0.f, 0.f, 0.f, 0.f};

  const int nk = K >> 5;
  const u16* Ab = (const u16*)A;

  for (int kt = 0; kt < nk; ++kt) {
    const int kg = kt << 5;
    __syncthreads();
    if (a_f32) {
      // A tile reg-staged with f32->bf16 conversion (linear layout)
#pragma unroll
      for (int i = 0; i < 2; ++i) {
        int ci = tid + i * 256;
        int row = ci >> 2, kc = (ci & 3) << 3;
        const float* Af = (const float*)A + (r0 + row) * (long)lda + kg + kc;
        float4 v0 = *(const float4*)Af;
        float4 v1 = *(const float4*)(Af + 4);
        ushort4 p0, p1;
        p0.x = f2b(v0.x); p0.y = f2b(v0.y); p0.z = f2b(v0.z); p0.w = f2b(v0.w);
        p1.x = f2b(v1.x); p1.y = f2b(v1.y); p1.z = f2b(v1.z); p1.w = f2b(v1.w);
        *(ushort4*)&As[row * 32 + kc] = p0;
        *(ushort4*)&As[row * 32 + kc + 4] = p1;
      }
    } else {
      // A tile: 1024 16B-chunks via global_load_lds (4 instrs/thread-group)
#pragma unroll
      for (int i = 0; i < 4; ++i) {
        int ci = tid + i * 256;                 // chunk = row*4 + qd
        int row = ci >> 2, kc = (ci & 3) << 3;
        GLDS16(Ab + (r0 + row) * (long)lda + kg + kc,
               &As[(i * 256 + wavebase) * 8]);  // + lane*16B by HW
      }
    }
    // B tile: 640 chunks (2.5 instrs/thread-group; tail waves 0-1 only)
#pragma unroll
    for (int i = 0; i < 2; ++i) {
      int ci = tid + i * 256;
      int row = ci >> 2, kc = (ci & 3) << 3;
      GLDS16(WT + (long)(c0 + row) * LD + kg + kc,
             &Bs[(i * 256 + wavebase) * 8]);
    }
    if (tid < 128) {
      int ci = tid + 512;
      int row = ci >> 2, kc = (ci & 3) << 3;
      GLDS16(WT + (long)(c0 + row) * LD + kg + kc,
             &Bs[(512 + wavebase) * 8]);
    }
    __syncthreads();   // compiler drains vmcnt(0)+lgkmcnt(0) before s_barrier

    short8 af[4], bf[5];
#pragma unroll
    for (int t = 0; t < 4; ++t) af[t] = *(const short8*)&As[(wm + t * 16 + m16) * 32 + (q << 3)];
#pragma unroll
    for (int t = 0; t < 5; ++t) bf[t] = *(const short8*)&Bs[(wn + t * 16 + m16) * 32 + (q << 3)];
#pragma unroll
    for (int tm = 0; tm < 4; ++tm)
#pragma unroll
      for (int tn = 0; tn < 5; ++tn)
        acc[tm][tn] = __builtin_amdgcn_mfma_f32_16x16x32_bf16(af[tm], bf[tn], acc[tm][tn], 0, 0, 0);
  }

  // D row = q*4+i, col = lane&15 (m89/m91-verified C/D layout)
#pragma unroll
  for (int tn = 0; tn < 5; ++tn) {
    int c = c0 + wn + tn * 16 + m16;
    float bv = bias[c];
#pragma unroll
    for (int tm = 0; tm < 4; ++tm) {
      long rbase = r0 + wm + tm * 16 + q * 4;
#pragma unroll
      for (int i = 0; i < 4; ++i) {
        float v = acc[tm][tn][i] + bv;
        if (relu) v = v > 0.f ? v : 0.f;
        C[(rbase + i) * LD + c] = f2b(v);
      }
    }
  }
}

// ---------------------------------------------------------------------------
// gather: z[n] = h[n] + sum_{t: dst-sorted edges of n} relu(h[src]+eraw@We+be)
// Best measured config (~158us). Thread owns one column; register
// accumulator; no LDS; 4-edge software batch (compiler-scheduled).
// Per-edge math order unchanged (bit-identical numerics).
// Pad cols (300..319) are exactly 0 everywhere -> no guards needed.
// ---------------------------------------------------------------------------
__global__ __launch_bounds__(320) void gather_kernel(
    const u16* __restrict__ h, const float* __restrict__ eraw,
    const u16* __restrict__ wtE, const float* __restrict__ biasE,
    const int2* __restrict__ ess, const int* __restrict__ indptr,
    u16* __restrict__ z)
{
  const int base = blockIdx.x * GNB;
  const int c = threadIdx.x;

  float wreg[16];
  {
    uint4 w0 = *(const uint4*)(wtE + (long)c * LD);
    uint4 w1 = *(const uint4*)(wtE + (long)c * LD + 8);
    const u16* pw0 = (const u16*)&w0;
    const u16* pw1 = (const u16*)&w1;
#pragma unroll
    for (int k = 0; k < 8; ++k) { wreg[k] = b2f(pw0[k]); wreg[8 + k] = b2f(pw1[k]); }
  }
  const float bv = biasE[c];

  const int t0 = indptr[base];
  const int t1 = indptr[base + GNB];

  int g = 0;                              // current node within block
  int nxt = indptr[base + 1];             // end of current node's edge range
  float s = b2f(h[(long)base * LD + c]);  // z = h + agg, eps = 0

  for (int tb = t0; tb < t1; tb += 4) {
    // tail-clamped edge indices (duplicates are guard-skipped below)
    const int tB = (tb + 1 < t1) ? tb + 1 : t1 - 1;
    const int tC = (tb + 2 < t1) ? tb + 2 : t1 - 1;
    const int tD = (tb + 3 < t1) ? tb + 3 : t1 - 1;
    int2 eA = ess[tb], eB = ess[tB], eC = ess[tC], eD = ess[tD];

    const float* rA = eraw + (long)eA.x * 16;
    const float* rB = eraw + (long)eB.x * 16;
    const float* rC = eraw + (long)eC.x * 16;
    const float* rD = eraw + (long)eD.x * 16;
    float4 A0 = *(const float4*)rA, A1 = *(const float4*)(rA + 4),
           A2 = *(const float4*)(rA + 8), A3 = *(const float4*)(rA + 12);
    float4 B0 = *(const float4*)rB, B1 = *(const float4*)(rB + 4),
           B2 = *(const float4*)(rB + 8), B3 = *(const float4*)(rB + 12);
    float4 C0 = *(const float4*)rC, C1 = *(const float4*)(rC + 4),
           C2 = *(const float4*)(rC + 8), C3 = *(const float4*)(rC + 12);
    float4 D0 = *(const float4*)rD, D1 = *(const float4*)(rD + 4),
           D2 = *(const float4*)(rD + 8), D3 = *(const float4*)(rD + 12);
    float hA = b2f(h[(long)eA.y * LD + c]);
    float hB = b2f(h[(long)eB.y * LD + c]);
    float hC = b2f(h[(long)eC.y * LD + c]);
    float hD = b2f(h[(long)eD.y * LD + c]);

    float mA = bv;
    mA += A0.x * wreg[0];  mA += A0.y * wreg[1];  mA += A0.z * wreg[2];  mA += A0.w * wreg[3];
    mA += A1.x * wreg[4];  mA += A1.y * wreg[5];  mA += A1.z * wreg[6];  mA += A1.w * wreg[7];
    mA += A2.x * wreg[8];  mA += A2.y * wreg[9];  mA += A2.z * wreg[10]; mA += A2.w * wreg[11];
    mA += A3.x * wreg[12]; mA += A3.y * wreg[13]; mA += A3.z * wreg[14]; mA += A3.w * wreg[15];
    mA += hA;
    float mB = bv;
    mB += B0.x * wreg[0];  mB += B0.y * wreg[1];  mB += B0.z * wreg[2];  mB += B0.w * wreg[3];
    mB += B1.x * wreg[4];  mB += B1.y * wreg[5];  mB += B1.z * wreg[6];  mB += B1.w * wreg[7];
    mB += B2.x * wreg[8];  mB += B2.y * wreg[9];  mB += B2.z * wreg[10]; mB += B2.w * wreg[11];
    mB += B3.x * wreg[12]; mB += B3.y * wreg[13]; mB += B3.z * wreg[14]; mB += B3.w * wreg[15];
    mB += hB;
    float mC = bv;
    mC += C0.x * wreg[0];  mC += C0.y * wreg[1];  mC += C0.z * wreg[2];  mC += C0.w * wreg[3];
    mC += C1.x * wreg[4];  mC += C1.y * wreg[5];  mC += C1.z * wreg[6];  mC += C1.w * wreg[7];
    mC += C2.x * wreg[8];  mC += C2.y * wreg[9];  mC += C2.z * wreg[10]; mC += C2.w * wreg[11];
    mC += C3.x * wreg[12]; mC += C3.y * wreg[13]; mC += C3.z * wreg[14]; mC += C3.w * wreg[15];
    mC += hC;
    float mD = bv;
    mD += D0.x * wreg[0];  mD += D0.y * wreg[1];  mD += D0.z * wreg[2];  mD += D0.w * wreg[3];
    mD += D1.x * wreg[4];  mD += D1.y * wreg[5];  mD += D1.z * wreg[6];  mD += D1.w * wreg[7];
    mD += D2.x * wreg[8];  mD += D2.y * wreg[9];  mD += D2.z * wreg[10]; mD += D2.w * wreg[11];
    mD += D3.x * wreg[12]; mD += D3.y * wreg[13]; mD += D3.z * wreg[14]; mD += D3.w * wreg[15];
    mD += hD;

#pragma unroll
    for (int j = 0; j < 4; ++j) {
      const float mj = (j == 0) ? mA : (j == 1) ? mB : (j == 2) ? mC : mD;
      const int t = tb + j;
      if (t < t1) {
        while (t >= nxt) {   // advance/flush (block-uniform branch)
          z[(long)(base + g) * LD + c] = f2b(s);
          ++g;
          s = b2f(h[(long)(base + g) * LD + c]);
          nxt = indptr[base + g + 1];
        }
        s += (mj > 0.f) ? mj : 0.f;
      }
    }
  }

  // flush the node in flight, then remaining (possibly empty) nodes as h-copy
  z[(long)(base + g) * LD + c] = f2b(s);
  for (++g; g < GNB; ++g) {
    s = b2f(h[(long)(base + g) * LD + c]);
    z[(long)(base + g) * LD + c] = f2b(s);
  }
}

// ---------------------------------------------------------------------------
// pooling: seg sorted -> block b binary-searches node range, no atomics
// ---------------------------------------------------------------------------
__global__ __launch_bounds__(320) void pool_kernel(
    const u16* __restrict__ h, const int* __restrict__ seg, float* __restrict__ acc)
{
  int b = blockIdx.x;
  int lo, hi;
  { int l = 0, r = NN; while (l < r) { int m = (l + r) >> 1; if (seg[m] < b) l = m + 1; else r = m; } lo = l; }
  { int l = lo, r = NN; while (l < r) { int m = (l + r) >> 1; if (seg[m] < b + 1) l = m + 1; else r = m; } hi = l; }
  int j = threadIdx.x;
  if (j < HH) {
    float s = 0.f;
    for (int n = lo; n < hi; ++n) s += b2f(h[(long)n * LD + j]);
    acc[(long)b * HH + j] += s;
  }
}

// out[0:BHSZ) = r - p, where r lives at out[BHSZ..) and p at out[2*BHSZ..)
__global__ __launch_bounds__(256) void combine_kernel(float* __restrict__ out) {
  int i = blockIdx.x * 256 + threadIdx.x;
  if (i < BHSZ) out[i] = out[BHSZ + i] - out[2 * BHSZ + i];
}

// ---------------------------------------------------------------------------
extern "C" void kernel_launch(void* const* d_in, const int* in_sizes, int n_in,
                              void* d_out, int out_size, void* d_ws, size_t ws_size,
                              hipStream_t stream)
{
  (void)in_sizes; (void)n_in; (void)out_size; (void)ws_size;
  const float* r_x = (const float*)d_in[0];
  const float* r_e = (const float*)d_in[1];
  const float* p_x = (const float*)d_in[2];
  const float* p_e = (const float*)d_in[3];
  const float* Wn  = (const float*)d_in[4];
  const float* bn  = (const float*)d_in[5];
  const float* We  = (const float*)d_in[6];
  const float* be  = (const float*)d_in[7];
  const float* W1  = (const float*)d_in[8];
  const float* b1  = (const float*)d_in[9];
  const float* W2  = (const float*)d_in[10];
  const float* b2  = (const float*)d_in[11];
  const int* r_src = (const int*)d_in[12];
  const int* r_dst = (const int*)d_in[13];
  const int* r_seg = (const int*)d_in[14];
  const int* p_src = (const int*)d_in[15];
  const int* p_dst = (const int*)d_in[16];
  const int* p_seg = (const int*)d_in[17];
  float* out = (float*)d_out;

  // --- workspace layout (~163 MB, proven to fit) ---
  char* ws = (char*)d_ws;
  size_t off = 0;
  auto take = [&](size_t bytes) -> char* {
    char* p = ws + off;
    off = (off + bytes + 255) & ~(size_t)255;
    return p;
  };
  u16*   nb0     = (u16*)  take((size_t)NN * LD * 2);       // h / t ping
  u16*   nb1     = (u16*)  take((size_t)NN * LD * 2);       // z / h pong
  u16*   wtAll   = (u16*)  take((size_t)8 * WTSL * 2);      // transposed weights
  float* biasAll = (float*)take((size_t)8 * NCP * 4);       // padded biases
  int*   indptr  = (int*)  take((size_t)(NN + 1) * 4);
  int*   cursor  = (int*)  take((size_t)NN * 4);
  int2*  ess     = (int2*) take((size_t)EE * 8);            // dst-sorted {eid,src}

  float* r_acc = out + BHSZ;       // pooled reactant sums (f32, output 1)
  float* p_acc = out + 2 * BHSZ;   // pooled product sums  (f32, output 2)

  prep_kernel<<<3852, 256, 0, stream>>>(Wn, We, W1, W2, bn, be, b1, b2, wtAll, biasAll);
  zero_kernel<<<2400, 256, 0, stream>>>((float4*)r_acc, 614400);   // r_acc + p_acc

  const float* xs[3] = { r_x, r_x + (size_t)NN * 64, p_x };
  const float* es[3] = { r_e, r_e + (size_t)EE * 16, p_e };
  const int* srcs[3] = { r_src, r_src + EE, p_src };
  const int* dsts[3] = { r_dst, r_dst + EE, p_dst };
  const int* segs[3] = { r_seg, r_seg + NN, p_seg };
  float*     accs[3] = { r_acc, r_acc, p_acc };

  for (int g = 0; g < 3; ++g) {
    // CSR by dst (reused across the 3 layers of this graph)
    zero_kernel<<<120, 256, 0, stream>>>((float4*)cursor, 30720);
    count_kernel<<<960, 256, 0, stream>>>(dsts[g], cursor);
    scan_kernel<<<1, 1024, 0, stream>>>(cursor, indptr);
    fill_kernel<<<960, 256, 0, stream>>>(dsts[g], srcs[g], cursor, ess);

    // h = relu(x @ Wn + bn)   (f32 A, K=64)
    gemm_kernel<<<dim3(NN / 128, 2), 256, 0, stream>>>(xs[g], 64, 64, 1,
        wtAll, biasAll, nb0, 1);

    u16* hA = nb0; u16* hB = nb1;
    for (int l = 0; l < 3; ++l) {
      gather_kernel<<<NN / GNB, 320, 0, stream>>>(hA, es[g], wtAll + WTSL,
          biasAll + NCP, ess, indptr, hB);
      // t = relu(z @ W1[l] + b1[l])
      gemm_kernel<<<dim3(NN / 128, 2), 256, 0, stream>>>(hB, LD, LD, 0,
          wtAll + (2 + l) * WTSL, biasAll + (2 + l) * NCP, hA, 1);
      // h = t @ W2[l] + b2[l]  (+relu if l<2)
      gemm_kernel<<<dim3(NN / 128, 2), 256, 0, stream>>>(hA, LD, LD, 0,
          wtAll + (5 + l) * WTSL, biasAll + (5 + l) * NCP, hB, (l < 2) ? 1 : 0);
      u16* tmp = hA; hA = hB; hB = tmp;
    }
    pool_kernel<<<BB, 320, 0, stream>>>(hA, segs[g], accs[g]);
  }
  combine_kernel<<<4800, 256, 0, stream>>>(out);
}

// Round 9
// 2877.458 us; speedup vs baseline: 1.9682x; 1.0260x over previous
//
#include <hip/hip_runtime.h>

typedef unsigned short u16;
typedef __attribute__((ext_vector_type(8))) short short8;
typedef __attribute__((ext_vector_type(4))) float f32x4;

#define NN 122880   // nodes per graph
#define EE 245760   // edges per graph
#define BB 4096     // reactions
#define HH 300      // hidden
#define LD 320      // padded feature leading dim (mult of 32)
#define NCP 384     // padded out-col count in WT slots
#define WTSL (NCP * LD)   // elements per transposed-weight slot
#define BHSZ (BB * HH)
#define GNB 16      // nodes per gather block (best measured config)

__device__ __forceinline__ float b2f(u16 s) {
  union { unsigned int u; float f; } v; v.u = ((unsigned int)s) << 16; return v.f;
}
__device__ __forceinline__ u16 f2b(float f) {
  union { float f; unsigned int u; } v; v.f = f;
  unsigned int r = v.u + 0x7FFFu + ((v.u >> 16) & 1u);
  return (u16)(r >> 16);
}

// async global->LDS, 16B per lane; LDS dest = wave-uniform base + lane*16
#define GLDS16(gp, lp) __builtin_amdgcn_global_load_lds( \
    (const __attribute__((address_space(1))) unsigned int*)(gp), \
    (__attribute__((address_space(3))) unsigned int*)(lp), 16, 0, 0)

// ---------------------------------------------------------------------------
// prep: f32 weights -> zero-padded transposed bf16 WT[slot][n(384)][k(320)],
// f32 biases -> padded f32 bias[slot][384]. Slots: 0=Wn 1=We 2..4=W1 5..7=W2
// ---------------------------------------------------------------------------
__global__ __launch_bounds__(256) void prep_kernel(
    const float* __restrict__ Wn, const float* __restrict__ We,
    const float* __restrict__ W1, const float* __restrict__ W2,
    const float* __restrict__ bn, const float* __restrict__ be,
    const float* __restrict__ b1, const float* __restrict__ b2,
    u16* __restrict__ wtAll, float* __restrict__ biasAll)
{
  int idx = blockIdx.x * 256 + threadIdx.x;
  if (idx < 8 * WTSL) {
    int slot = idx / WTSL, rem = idx % WTSL;
    int n = rem / LD, k = rem % LD;
    float v = 0.f;
    if (n < HH) {
      if (slot == 0)      { if (k < 64)  v = Wn[k * HH + n]; }
      else if (slot == 1) { if (k < 16)  v = We[k * HH + n]; }
      else if (slot < 5)  { int l = slot - 2; if (k < HH) v = W1[(l * HH + k) * HH + n]; }
      else                { int l = slot - 5; if (k < HH) v = W2[(l * HH + k) * HH + n]; }
    }
    wtAll[idx] = f2b(v);
  } else {
    int j = idx - 8 * WTSL;
    if (j < 8 * NCP) {
      int slot = j / NCP, n = j % NCP;
      float v = 0.f;
      if (n < HH) {
        const float* bp = (slot == 0) ? bn : (slot == 1) ? be
                         : (slot < 5) ? (b1 + (slot - 2) * HH) : (b2 + (slot - 5) * HH);
        v = bp[n];
      }
      biasAll[j] = v;
    }
  }
}

__global__ __launch_bounds__(256) void zero_kernel(float4* __restrict__ p, int n4) {
  int i = blockIdx.x * 256 + threadIdx.x;
  if (i < n4) p[i] = make_float4(0.f, 0.f, 0.f, 0.f);
}

// ---------------------------------------------------------------------------
// CSR build: cursor doubles as counts; scan converts in place.
// fill writes int2{edge id, src id}, dst-sorted.
// ---------------------------------------------------------------------------
__global__ __launch_bounds__(256) void count_kernel(
    const int* __restrict__ dst, int* __restrict__ cursor)
{
  int e = blockIdx.x * 256 + threadIdx.x;
  if (e < EE) atomicAdd(&cursor[dst[e]], 1);
}

__global__ __launch_bounds__(1024) void scan_kernel(
    int* __restrict__ cursor, int* __restrict__ indptr)
{
  __shared__ int sd[1024];
  const int tid = threadIdx.x;
  const int base = tid * 120;          // 1024 * 120 == NN exactly
  int s = 0;
  for (int i = 0; i < 120; ++i) s += cursor[base + i];
  sd[tid] = s;
  __syncthreads();
  for (int off = 1; off < 1024; off <<= 1) {
    int v = (tid >= off) ? sd[tid - off] : 0;
    __syncthreads();
    sd[tid] += v;
    __syncthreads();
  }
  int run = sd[tid] - s;               // exclusive prefix
  for (int i = 0; i < 120; ++i) {
    int c = cursor[base + i];
    indptr[base + i] = run;
    cursor[base + i] = run;
    run += c;
  }
  if (tid == 1023) indptr[NN] = run;   // == EE
}

__global__ __launch_bounds__(256) void fill_kernel(
    const int* __restrict__ dst, const int* __restrict__ src,
    int* __restrict__ cursor, int2* __restrict__ ess)
{
  int e = blockIdx.x * 256 + threadIdx.x;
  if (e < EE) {
    int pos = atomicAdd(&cursor[dst[e]], 1);
    ess[pos] = make_int2(e, src[e]);
  }
}

// ---------------------------------------------------------------------------
// edgeprep: remove the gather's double indirection once per graph.
// eperm[t] = eraw[ess[t].x]  (f32, dst-sorted copy, bit-identical data)
// hsrc[t]  = ess[t].y
// Gather then reads eperm/hsrc at LINEAR addresses; only h[src] stays random.
// ---------------------------------------------------------------------------
__global__ __launch_bounds__(256) void edgeprep_kernel(
    const float* __restrict__ eraw, const int2* __restrict__ ess,
    float4* __restrict__ eperm, int* __restrict__ hsrc)
{
  int t = blockIdx.x * 256 + threadIdx.x;
  if (t < EE) {
    int2 es = ess[t];
    const float4* er = (const float4*)(eraw + (long)es.x * 16);
    float4 a = er[0], b = er[1], c = er[2], d = er[3];
    eperm[(long)t * 4 + 0] = a;
    eperm[(long)t * 4 + 1] = b;
    eperm[(long)t * 4 + 2] = c;
    eperm[(long)t * 4 + 3] = d;
    hsrc[t] = es.y;
  }
}

// ---------------------------------------------------------------------------
// MFMA GEMM (R8 proven: global_load_lds width=16 staging, linear LDS).
// C[r,c] = op(A[r,:K] @ W[:K,c] + bias[c]), bf16 out. Tile 128x160,
// grid.y=2, 4 waves 2x2, wave = 4x5 MFMA 16x16x32. Chunk (row,q) at byte
// offset row*64 + q*16. f32-A path (K=64) reg-stages with conversion.
// ---------------------------------------------------------------------------
__global__ __launch_bounds__(256) void gemm_kernel(
    const void* __restrict__ A, int lda, int K, int a_f32,
    const u16* __restrict__ WT, const float* __restrict__ bias,
    u16* __restrict__ C, int relu)
{
  __shared__ u16 As[128 * 32];   // 16 KB, linear
  __shared__ u16 Bs[160 * 32];   // 10 KB, linear

  const int tid = threadIdx.x;
  const int lane = tid & 63, w = tid >> 6;
  const int wm = (w >> 1) * 64, wn = (w & 1) * 80;
  const int m16 = lane & 15, q = lane >> 4;
  const long r0 = (long)blockIdx.x * 128;
  const int c0 = blockIdx.y * 160;
  const int wavebase = tid & 0xC0;     // wave-uniform lane-group base (chunks)

  f32x4 acc[4][5];
#pragma unroll
  for (int i = 0; i < 4; ++i)
#pragma unroll
    for (int j = 0; j < 5; ++j) acc[i][j] = (f32x4){0.f, 0.f, 0.f, 0.f};

  const int nk = K >> 5;
  const u16* Ab = (const u16*)A;

  for (int kt = 0; kt < nk; ++kt) {
    const int kg = kt << 5;
    __syncthreads();
    if (a_f32) {
      // A tile reg-staged with f32->bf16 conversion (linear layout)
#pragma unroll
      for (int i = 0; i < 2; ++i) {
        int ci = tid + i * 256;
        int row = ci >> 2, kc = (ci & 3) << 3;
        const float* Af = (const float*)A + (r0 + row) * (long)lda + kg + kc;
        float4 v0 = *(const float4*)Af;
        float4 v1 = *(const float4*)(Af + 4);
        ushort4 p0, p1;
        p0.x = f2b(v0.x); p0.y = f2b(v0.y); p0.z = f2b(v0.z); p0.w = f2b(v0.w);
        p1.x = f2b(v1.x); p1.y = f2b(v1.y); p1.z = f2b(v1.z); p1.w = f2b(v1.w);
        *(ushort4*)&As[row * 32 + kc] = p0;
        *(ushort4*)&As[row * 32 + kc + 4] = p1;
      }
    } else {
      // A tile: 1024 16B-chunks via global_load_lds (4 instrs/thread-group)
#pragma unroll
      for (int i = 0; i < 4; ++i) {
        int ci = tid + i * 256;                 // chunk = row*4 + qd
        int row = ci >> 2, kc = (ci & 3) << 3;
        GLDS16(Ab + (r0 + row) * (long)lda + kg + kc,
               &As[(i * 256 + wavebase) * 8]);  // + lane*16B by HW
      }
    }
    // B tile: 640 chunks (2.5 instrs/thread-group; tail waves 0-1 only)
#pragma unroll
    for (int i = 0; i < 2; ++i) {
      int ci = tid + i * 256;
      int row = ci >> 2, kc = (ci & 3) << 3;
      GLDS16(WT + (long)(c0 + row) * LD + kg + kc,
             &Bs[(i * 256 + wavebase) * 8]);
    }
    if (tid < 128) {
      int ci = tid + 512;
      int row = ci >> 2, kc = (ci & 3) << 3;
      GLDS16(WT + (long)(c0 + row) * LD + kg + kc,
             &Bs[(512 + wavebase) * 8]);
    }
    __syncthreads();   // compiler drains vmcnt(0)+lgkmcnt(0) before s_barrier

    short8 af[4], bf[5];
#pragma unroll
    for (int t = 0; t < 4; ++t) af[t] = *(const short8*)&As[(wm + t * 16 + m16) * 32 + (q << 3)];
#pragma unroll
    for (int t = 0; t < 5; ++t) bf[t] = *(const short8*)&Bs[(wn + t * 16 + m16) * 32 + (q << 3)];
#pragma unroll
    for (int tm = 0; tm < 4; ++tm)
#pragma unroll
      for (int tn = 0; tn < 5; ++tn)
        acc[tm][tn] = __builtin_amdgcn_mfma_f32_16x16x32_bf16(af[tm], bf[tn], acc[tm][tn], 0, 0, 0);
  }

  // D row = q*4+i, col = lane&15 (m89/m91-verified C/D layout)
#pragma unroll
  for (int tn = 0; tn < 5; ++tn) {
    int c = c0 + wn + tn * 16 + m16;
    float bv = bias[c];
#pragma unroll
    for (int tm = 0; tm < 4; ++tm) {
      long rbase = r0 + wm + tm * 16 + q * 4;
#pragma unroll
      for (int i = 0; i < 4; ++i) {
        float v = acc[tm][tn][i] + bv;
        if (relu) v = v > 0.f ? v : 0.f;
        C[(rbase + i) * LD + c] = f2b(v);
      }
    }
  }
}

// ---------------------------------------------------------------------------
// gather: z[n] = h[n] + sum_{t: dst-sorted edges of n} relu(h[src]+e@We+be)
// v2: edge features pre-permuted (eperm, f32) and src ids (hsrc) are read at
// LINEAR addresses -> no ess->eraw dependent-load chain; the only dependent
// load left is hsrc->h[src]. Per-edge math order unchanged (bit-identical).
// Thread owns one column; register accumulator; no LDS.
// ---------------------------------------------------------------------------
__global__ __launch_bounds__(320) void gather_kernel(
    const u16* __restrict__ h, const float* __restrict__ eperm,
    const int* __restrict__ hsrc,
    const u16* __restrict__ wtE, const float* __restrict__ biasE,
    const int* __restrict__ indptr, u16* __restrict__ z)
{
  const int base = blockIdx.x * GNB;
  const int c = threadIdx.x;

  float wreg[16];
  {
    uint4 w0 = *(const uint4*)(wtE + (long)c * LD);
    uint4 w1 = *(const uint4*)(wtE + (long)c * LD + 8);
    const u16* pw0 = (const u16*)&w0;
    const u16* pw1 = (const u16*)&w1;
#pragma unroll
    for (int k = 0; k < 8; ++k) { wreg[k] = b2f(pw0[k]); wreg[8 + k] = b2f(pw1[k]); }
  }
  const float bv = biasE[c];

  const int t0 = indptr[base];
  const int t1 = indptr[base + GNB];

  int g = 0;                              // current node within block
  int nxt = indptr[base + 1];             // end of current node's edge range
  float s = b2f(h[(long)base * LD + c]);  // z = h + agg, eps = 0

  for (int tb = t0; tb < t1; tb += 4) {
    // tail-clamped edge indices (duplicates are guard-skipped below)
    const int tB = (tb + 1 < t1) ? tb + 1 : t1 - 1;
    const int tC = (tb + 2 < t1) ? tb + 2 : t1 - 1;
    const int tD = (tb + 3 < t1) ? tb + 3 : t1 - 1;

    // linear loads: no dependency on any prior load
    const int sA = hsrc[tb], sB = hsrc[tB], sC = hsrc[tC], sD = hsrc[tD];
    const float* rA = eperm + (long)tb * 16;
    const float* rB = eperm + (long)tB * 16;
    const float* rC = eperm + (long)tC * 16;
    const float* rD = eperm + (long)tD * 16;
    float4 A0 = *(const float4*)rA, A1 = *(const float4*)(rA + 4),
           A2 = *(const float4*)(rA + 8), A3 = *(const float4*)(rA + 12);
    float4 B0 = *(const float4*)rB, B1 = *(const float4*)(rB + 4),
           B2 = *(const float4*)(rB + 8), B3 = *(const float4*)(rB + 12);
    float4 C0 = *(const float4*)rC, C1 = *(const float4*)(rC + 4),
           C2 = *(const float4*)(rC + 8), C3 = *(const float4*)(rC + 12);
    float4 D0 = *(const float4*)rD, D1 = *(const float4*)(rD + 4),
           D2 = *(const float4*)(rD + 8), D3 = *(const float4*)(rD + 12);
    // the single dependent load level: hsrc -> h row
    float hA = b2f(h[(long)sA * LD + c]);
    float hB = b2f(h[(long)sB * LD + c]);
    float hC = b2f(h[(long)sC * LD + c]);
    float hD = b2f(h[(long)sD * LD + c]);

    float mA = bv;
    mA += A0.x * wreg[0];  mA += A0.y * wreg[1];  mA += A0.z * wreg[2];  mA += A0.w * wreg[3];
    mA += A1.x * wreg[4];  mA += A1.y * wreg[5];  mA += A1.z * wreg[6];  mA += A1.w * wreg[7];
    mA += A2.x * wreg[8];  mA += A2.y * wreg[9];  mA += A2.z * wreg[10]; mA += A2.w * wreg[11];
    mA += A3.x * wreg[12]; mA += A3.y * wreg[13]; mA += A3.z * wreg[14]; mA += A3.w * wreg[15];
    mA += hA;
    float mB = bv;
    mB += B0.x * wreg[0];  mB += B0.y * wreg[1];  mB += B0.z * wreg[2];  mB += B0.w * wreg[3];
    mB += B1.x * wreg[4];  mB += B1.y * wreg[5];  mB += B1.z * wreg[6];  mB += B1.w * wreg[7];
    mB += B2.x * wreg[8];  mB += B2.y * wreg[9];  mB += B2.z * wreg[10]; mB += B2.w * wreg[11];
    mB += B3.x * wreg[12]; mB += B3.y * wreg[13]; mB += B3.z * wreg[14]; mB += B3.w * wreg[15];
    mB += hB;
    float mC = bv;
    mC += C0.x * wreg[0];  mC += C0.y * wreg[1];  mC += C0.z * wreg[2];  mC += C0.w * wreg[3];
    mC += C1.x * wreg[4];  mC += C1.y * wreg[5];  mC += C1.z * wreg[6];  mC += C1.w * wreg[7];
    mC += C2.x * wreg[8];  mC += C2.y * wreg[9];  mC += C2.z * wreg[10]; mC += C2.w * wreg[11];
    mC += C3.x * wreg[12]; mC += C3.y * wreg[13]; mC += C3.z * wreg[14]; mC += C3.w * wreg[15];
    mC += hC;
    float mD = bv;
    mD += D0.x * wreg[0];  mD += D0.y * wreg[1];  mD += D0.z * wreg[2];  mD += D0.w * wreg[3];
    mD += D1.x * wreg[4];  mD += D1.y * wreg[5];  mD += D1.z * wreg[6];  mD += D1.w * wreg[7];
    mD += D2.x * wreg[8];  mD += D2.y * wreg[9];  mD += D2.z * wreg[10]; mD += D2.w * wreg[11];
    mD += D3.x * wreg[12]; mD += D3.y * wreg[13]; mD += D3.z * wreg[14]; mD += D3.w * wreg[15];
    mD += hD;

#pragma unroll
    for (int j = 0; j < 4; ++j) {
      const float mj = (j == 0) ? mA : (j == 1) ? mB : (j == 2) ? mC : mD;
      const int t = tb + j;
      if (t < t1) {
        while (t >= nxt) {   // advance/flush (block-uniform branch)
          z[(long)(base + g) * LD + c] = f2b(s);
          ++g;
          s = b2f(h[(long)(base + g) * LD + c]);
          nxt = indptr[base + g + 1];
        }
        s += (mj > 0.f) ? mj : 0.f;
      }
    }
  }

  // flush the node in flight, then remaining (possibly empty) nodes as h-copy
  z[(long)(base + g) * LD + c] = f2b(s);
  for (++g; g < GNB; ++g) {
    s = b2f(h[(long)(base + g) * LD + c]);
    z[(long)(base + g) * LD + c] = f2b(s);
  }
}

// ---------------------------------------------------------------------------
// pooling: seg sorted -> block b binary-searches node range, no atomics
// ---------------------------------------------------------------------------
__global__ __launch_bounds__(320) void pool_kernel(
    const u16* __restrict__ h, const int* __restrict__ seg, float* __restrict__ acc)
{
  int b = blockIdx.x;
  int lo, hi;
  { int l = 0, r = NN; while (l < r) { int m = (l + r) >> 1; if (seg[m] < b) l = m + 1; else r = m; } lo = l; }
  { int l = lo, r = NN; while (l < r) { int m = (l + r) >> 1; if (seg[m] < b + 1) l = m + 1; else r = m; } hi = l; }
  int j = threadIdx.x;
  if (j < HH) {
    float s = 0.f;
    for (int n = lo; n < hi; ++n) s += b2f(h[(long)n * LD + j]);
    acc[(long)b * HH + j] += s;
  }
}

// out[0:BHSZ) = r - p, where r lives at out[BHSZ..) and p at out[2*BHSZ..)
__global__ __launch_bounds__(256) void combine_kernel(float* __restrict__ out) {
  int i = blockIdx.x * 256 + threadIdx.x;
  if (i < BHSZ) out[i] = out[BHSZ + i] - out[2 * BHSZ + i];
}

// ---------------------------------------------------------------------------
extern "C" void kernel_launch(void* const* d_in, const int* in_sizes, int n_in,
                              void* d_out, int out_size, void* d_ws, size_t ws_size,
                              hipStream_t stream)
{
  (void)in_sizes; (void)n_in; (void)out_size; (void)ws_size;
  const float* r_x = (const float*)d_in[0];
  const float* r_e = (const float*)d_in[1];
  const float* p_x = (const float*)d_in[2];
  const float* p_e = (const float*)d_in[3];
  const float* Wn  = (const float*)d_in[4];
  const float* bn  = (const float*)d_in[5];
  const float* We  = (const float*)d_in[6];
  const float* be  = (const float*)d_in[7];
  const float* W1  = (const float*)d_in[8];
  const float* b1  = (const float*)d_in[9];
  const float* W2  = (const float*)d_in[10];
  const float* b2  = (const float*)d_in[11];
  const int* r_src = (const int*)d_in[12];
  const int* r_dst = (const int*)d_in[13];
  const int* r_seg = (const int*)d_in[14];
  const int* p_src = (const int*)d_in[15];
  const int* p_dst = (const int*)d_in[16];
  const int* p_seg = (const int*)d_in[17];
  float* out = (float*)d_out;

  // --- workspace layout (~180 MB) ---
  char* ws = (char*)d_ws;
  size_t off = 0;
  auto take = [&](size_t bytes) -> char* {
    char* p = ws + off;
    off = (off + bytes + 255) & ~(size_t)255;
    return p;
  };
  u16*   nb0     = (u16*)  take((size_t)NN * LD * 2);       // h / t ping
  u16*   nb1     = (u16*)  take((size_t)NN * LD * 2);       // z / h pong
  u16*   wtAll   = (u16*)  take((size_t)8 * WTSL * 2);      // transposed weights
  float* biasAll = (float*)take((size_t)8 * NCP * 4);       // padded biases
  int*   indptr  = (int*)  take((size_t)(NN + 1) * 4);
  int*   cursor  = (int*)  take((size_t)NN * 4);
  int2*  ess     = (int2*) take((size_t)EE * 8);            // dst-sorted {eid,src}
  float* eperm   = (float*)take((size_t)EE * 16 * 4);       // dst-sorted edge feats (f32)
  int*   hsrc    = (int*)  take((size_t)EE * 4);            // dst-sorted src ids

  float* r_acc = out + BHSZ;       // pooled reactant sums (f32, output 1)
  float* p_acc = out + 2 * BHSZ;   // pooled product sums  (f32, output 2)

  prep_kernel<<<3852, 256, 0, stream>>>(Wn, We, W1, W2, bn, be, b1, b2, wtAll, biasAll);
  zero_kernel<<<2400, 256, 0, stream>>>((float4*)r_acc, 614400);   // r_acc + p_acc

  const float* xs[3] = { r_x, r_x + (size_t)NN * 64, p_x };
  const float* es[3] = { r_e, r_e + (size_t)EE * 16, p_e };
  const int* srcs[3] = { r_src, r_src + EE, p_src };
  const int* dsts[3] = { r_dst, r_dst + EE, p_dst };
  const int* segs[3] = { r_seg, r_seg + NN, p_seg };
  float*     accs[3] = { r_acc, r_acc, p_acc };

  for (int g = 0; g < 3; ++g) {
    // CSR by dst (reused across the 3 layers of this graph)
    zero_kernel<<<120, 256, 0, stream>>>((float4*)cursor, 30720);
    count_kernel<<<960, 256, 0, stream>>>(dsts[g], cursor);
    scan_kernel<<<1, 1024, 0, stream>>>(cursor, indptr);
    fill_kernel<<<960, 256, 0, stream>>>(dsts[g], srcs[g], cursor, ess);
    edgeprep_kernel<<<960, 256, 0, stream>>>(es[g], ess, (float4*)eperm, hsrc);

    // h = relu(x @ Wn + bn)   (f32 A, K=64)
    gemm_kernel<<<dim3(NN / 128, 2), 256, 0, stream>>>(xs[g], 64, 64, 1,
        wtAll, biasAll, nb0, 1);

    u16* hA = nb0; u16* hB = nb1;
    for (int l = 0; l < 3; ++l) {
      gather_kernel<<<NN / GNB, 320, 0, stream>>>(hA, eperm, hsrc,
          wtAll + WTSL, biasAll + NCP, indptr, hB);
      // t = relu(z @ W1[l] + b1[l])
      gemm_kernel<<<dim3(NN / 128, 2), 256, 0, stream>>>(hB, LD, LD, 0,
          wtAll + (2 + l) * WTSL, biasAll + (2 + l) * NCP, hA, 1);
      // h = t @ W2[l] + b2[l]  (+relu if l<2)
      gemm_kernel<<<dim3(NN / 128, 2), 256, 0, stream>>>(hA, LD, LD, 0,
          wtAll + (5 + l) * WTSL, biasAll + (5 + l) * NCP, hB, (l < 2) ? 1 : 0);
      u16* tmp = hA; hA = hB; hB = tmp;
    }
    pool_kernel<<<BB, 320, 0, stream>>>(hA, segs[g], accs[g]);
  }
  combine_kernel<<<4800, 256, 0, stream>>>(out);
}